// Round 5
// baseline (696.928 us; speedup 1.0000x reference)
//
#include <hip/hip_runtime.h>

typedef __bf16 bf16;
typedef bf16 bf16x8 __attribute__((ext_vector_type(8)));
typedef bf16 bf16x4 __attribute__((ext_vector_type(4)));
typedef short short4v __attribute__((ext_vector_type(4)));
typedef float f32x4 __attribute__((ext_vector_type(4)));

#define NPIX 196
#define CIN 384
#define NHEADS 12
#define MPAD 224
#define VSTRIDE 232   // LDS row stride for V (bf16): ~2-way banks
#define OSTRIDE 40    // LDS row stride for store-transpose chunk
#define TSTRIDE 136   // LDS row stride for kt transpose epilogue

// flag-aware scalar load: f=1 -> fp32 data, f=0 -> bf16 data
__device__ __forceinline__ float ldf(const void* p, size_t i, int f) {
    return f ? ((const float*)p)[i] : (float)((const bf16*)p)[i];
}

// bijective chunked XCD swizzle (m204): consecutive hw block ids round-robin
// across 8 XCDs; remap so each XCD owns a CONTIGUOUS logical range.
__device__ __forceinline__ int xcd_swizzle(int orig, int nwg) {
    int q = nwg >> 3, r = nwg & 7;
    int xcd = orig & 7, idx = orig >> 3;
    return (xcd < r ? xcd * (q + 1) : r * (q + 1) + (xcd - r) * q) + idx;
}

// K=16 bf16 MFMA: B-frag layout (lane l: col=l&15, k=(l>>4)*4+j) matches the
// in-register P layout produced by the swapped QK^T (m = grp*4 + r).
__device__ __forceinline__ f32x4 mfma16(bf16x4 a, bf16x4 b, f32x4 c) {
#if __has_builtin(__builtin_amdgcn_mfma_f32_16x16x16bf16_1k)
    return __builtin_amdgcn_mfma_f32_16x16x16bf16_1k(
        __builtin_bit_cast(short4v, a), __builtin_bit_cast(short4v, b), c, 0, 0, 0);
#else
    asm volatile("v_mfma_f32_16x16x16_bf16 %0, %1, %2, %0" : "+v"(c) : "v"(a), "v"(b));
    return c;
#endif
}

__device__ __forceinline__ f32x4 vmax4(f32x4 a, f32x4 b) {
    f32x4 r;
    r[0] = fmaxf(a[0], b[0]);
    r[1] = fmaxf(a[1], b[1]);
    r[2] = fmaxf(a[2], b[2]);
    r[3] = fmaxf(a[3], b[3]);
    return r;
}

// ---------------- dtype detector ----------------
__global__ void detect_kernel(const unsigned int* __restrict__ x, int* __restrict__ flag) {
    __shared__ int cnt;
    if (threadIdx.x == 0) cnt = 0;
    __syncthreads();
    int c = 0;
#pragma unroll
    for (int k = 0; k < 8; k++) {
        unsigned int w = x[threadIdx.x * 8 + k];
        unsigned int e = (w >> 7) & 0xFFu;
        if (e > 200u) c++;
    }
    atomicAdd(&cnt, c);
    __syncthreads();
    if (threadIdx.x == 0) *flag = (cnt >= 16) ? 1 : 0;
}

// ---------------- canonicalize weights to bf16 ----------------
__global__ void convert_kernel(const void* __restrict__ src, bf16* __restrict__ dst, int n,
                               const int* __restrict__ flag) {
    int f = *flag;
    for (int i = blockIdx.x * 256 + threadIdx.x; i < n; i += gridDim.x * 256)
        dst[i] = (bf16)ldf(src, i, f);
}

// ---------------- transpose x: (b, c, hw) -> (b, hw, c), canonical bf16 ----------------
__global__ void transpose_x_kernel(const void* __restrict__ x, const int* __restrict__ flag,
                                   bf16* __restrict__ xt, int b0) {
    __shared__ bf16 tile[32][33];
    int f = *flag;
    int b = blockIdx.z, gb = b0 + b;
    int c0 = blockIdx.y * 32;
    int hw0 = blockIdx.x * 32;
    int tx = threadIdx.x, ty = threadIdx.y;
    int hw = hw0 + tx, c = c0 + ty;
    if (hw < NPIX) tile[ty][tx] = (bf16)ldf(x, ((size_t)gb * CIN + c) * NPIX + hw, f);
    __syncthreads();
    int hw2 = hw0 + ty, c2 = c0 + tx;
    if (hw2 < NPIX) xt[((size_t)b * NPIX + hw2) * CIN + c2] = tile[tx][ty];
}

// ---------------- 128x128 GEMM mainloop: zero-LDS, register double-buffered ----------------
// K is tiny and every A/B byte is used once per block => LDS adds no reuse, and
// the measured bottleneck was the LDS read pipe (16 ds_read_b128 per 32 MFMA).
// MFMA fragments are loaded DIRECTLY global->VGPR: a wave's bf16x8 load covers
// 16 rows x 64B = 16 full cache lines (perfect VMEM efficiency, L2-served via
// XCD swizzle). Two named frag buffers (static indexing), loads for step k+1
// issued before the 32 MFMAs of step k (~310cyc cover vs ~200cyc L2 latency).
// No barriers: waves slip freely, TLP hides residual latency.
// Requires K % 128 == 0 (pairs of 64-wide K-steps).
template <int K>
__device__ __forceinline__ void gemm_direct(const bf16* __restrict__ A, const bf16* __restrict__ B,
                                            f32x4 acc[4][4]) {
    int tid = threadIdx.x;
    int wave = tid >> 6, lane = tid & 63;
    int wm = wave >> 1, wn = wave & 1;
    int row = lane & 15, grp = lane >> 4;
    const bf16* Ab = A + (size_t)(wm * 64 + row) * K + grp * 8;
    const bf16* Bb = B + (size_t)(wn * 64 + row) * K + grp * 8;
    bf16x8 a0[8], b0[8], a1[8], b1[8];
    // frag f = ki*4 + t: row offset t*16, k offset kb + ki*32 + grp*8(in base)
#define LOADF(aa, bb, kb)                                                         \
    {                                                                             \
        _Pragma("unroll") for (int f_ = 0; f_ < 8; f_++) {                        \
            int t_ = f_ & 3, ki_ = f_ >> 2;                                       \
            aa[f_] = *(const bf16x8*)(Ab + (size_t)(t_ * 16) * K + (kb) + ki_ * 32); \
            bb[f_] = *(const bf16x8*)(Bb + (size_t)(t_ * 16) * K + (kb) + ki_ * 32); \
        }                                                                         \
    }
#define COMPF(aa, bb)                                                             \
    _Pragma("unroll") for (int ki_ = 0; ki_ < 2; ki_++)                           \
    _Pragma("unroll") for (int mt_ = 0; mt_ < 4; mt_++)                           \
    _Pragma("unroll") for (int nt_ = 0; nt_ < 4; nt_++)                           \
        acc[mt_][nt_] = __builtin_amdgcn_mfma_f32_16x16x32_bf16(                  \
            aa[ki_ * 4 + mt_], bb[ki_ * 4 + nt_], acc[mt_][nt_], 0, 0, 0);

    LOADF(a0, b0, 0);
#pragma unroll 1
    for (int kb = 0; kb < K; kb += 128) {
        LOADF(a1, b1, kb + 64);
        COMPF(a0, b0);
        if (kb + 128 < K) LOADF(a0, b0, kb + 128);
        COMPF(a1, b1);
    }
#undef LOADF
#undef COMPF
}

// ---------------- QKV GEMM + BN, routed outputs ----------------
__global__ __launch_bounds__(256) void gemm_qkv_kernel(
    const bf16* __restrict__ xt, const bf16* __restrict__ w,
    const void* __restrict__ g, const void* __restrict__ bb,
    const void* __restrict__ mm, const void* __restrict__ vv, const int* __restrict__ flag,
    bf16* __restrict__ qb, bf16* __restrict__ kt, bf16* __restrict__ vb) {
    __shared__ bf16 tbuf[128 * TSTRIDE];   // kt transpose epilogue only (34816B)
    f32x4 acc[4][4];
#pragma unroll
    for (int i = 0; i < 4; i++)
#pragma unroll
        for (int j = 0; j < 4; j++) acc[i][j] = (f32x4){0.f, 0.f, 0.f, 0.f};
    // XCD swizzle: all 18 m-tiles of contiguous n-tile ranges land on one XCD,
    // so the shared 98KB B-tile is fetched from HBM once and served from L2.
    int nwg = gridDim.x * gridDim.y;
    int l = xcd_swizzle(blockIdx.y * gridDim.x + blockIdx.x, nwg);
    int m0 = (l % gridDim.x) * 128, n0 = (l / gridDim.x) * 128;
    gemm_direct<CIN>(w + (size_t)m0 * CIN, xt + (size_t)n0 * CIN, acc);
    int f = *flag;
    int tid = threadIdx.x;
    int wave = tid >> 6, lane = tid & 63;
    int wm = wave >> 1, wn = wave & 1, row = lane & 15, grp = lane >> 4;
    if (m0 >= 384 && m0 < 768) {
        // k-part: direct stores scatter 64 lines/wave-store (row stride 768B).
        // Transpose through LDS -> 256B-contiguous rows.
#pragma unroll
        for (int mt = 0; mt < 4; mt++) {
#pragma unroll
            for (int r = 0; r < 4; r++) {
                int ol = wm * 64 + mt * 16 + grp * 4 + r;
                int o = m0 + ol;
                float scv = ldf(g, o, f) * rsqrtf(ldf(vv, o, f) + 1e-5f);
                float sh = ldf(bb, o, f) - ldf(mm, o, f) * scv;
#pragma unroll
                for (int nt = 0; nt < 4; nt++) {
                    int nl = wn * 64 + nt * 16 + row;
                    tbuf[nl * TSTRIDE + ol] = (bf16)(acc[mt][nt][r] * scv + sh);
                }
            }
        }
        __syncthreads();
        // kt row address is LINEAR in n: (b*196+hw)*384 = n*384.
#pragma unroll
        for (int it = 0; it < 8; it++) {
            int g2 = it * 256 + tid;            // 2048 granules of 16B
            int nl = g2 >> 4, ch = g2 & 15;
            *(bf16x8*)(kt + (size_t)(n0 + nl) * CIN + (m0 - 384) + ch * 8) =
                *(const bf16x8*)(tbuf + nl * TSTRIDE + ch * 8);
        }
    } else {
#pragma unroll
        for (int mt = 0; mt < 4; mt++) {
#pragma unroll
            for (int r = 0; r < 4; r++) {
                int o = m0 + wm * 64 + mt * 16 + grp * 4 + r;
                float scv = ldf(g, o, f) * rsqrtf(ldf(vv, o, f) + 1e-5f);
                float sh = ldf(bb, o, f) - ldf(mm, o, f) * scv;
#pragma unroll
                for (int nt = 0; nt < 4; nt++) {
                    int n = n0 + wn * 64 + nt * 16 + row;
                    int b = n / NPIX, hw = n - b * NPIX;
                    float val = acc[mt][nt][r] * scv + sh;
                    bf16 bv = (bf16)val;
                    if (o < 384) {
                        qb[((size_t)b * 384 + o) * NPIX + hw] = bv;
                    } else {
                        vb[((size_t)b * 1536 + (o - 768)) * MPAD + hw] = bv;
                    }
                }
            }
        }
    }
}

// ---------------- proj GEMM + BN -> output ----------------
__global__ __launch_bounds__(256) void gemm_proj_kernel(
    const bf16* __restrict__ ot, const bf16* __restrict__ w,
    const void* __restrict__ g, const void* __restrict__ bb,
    const void* __restrict__ mm, const void* __restrict__ vv, const int* __restrict__ flag,
    void* __restrict__ out, int b0) {
    f32x4 acc[4][4];
#pragma unroll
    for (int i = 0; i < 4; i++)
#pragma unroll
        for (int j = 0; j < 4; j++) acc[i][j] = (f32x4){0.f, 0.f, 0.f, 0.f};
    int nwg = gridDim.x * gridDim.y;
    int l = xcd_swizzle(blockIdx.y * gridDim.x + blockIdx.x, nwg);
    int m0 = (l % gridDim.x) * 128, n0 = (l / gridDim.x) * 128;
    gemm_direct<1536>(w + (size_t)m0 * 1536, ot + (size_t)n0 * 1536, acc);
    int f = *flag;
    int wave = threadIdx.x >> 6, lane = threadIdx.x & 63;
    int wm = wave >> 1, wn = wave & 1, row = lane & 15, grp = lane >> 4;
#pragma unroll
    for (int mt = 0; mt < 4; mt++) {
#pragma unroll
        for (int r = 0; r < 4; r++) {
            int o = m0 + wm * 64 + mt * 16 + grp * 4 + r;
            float scv = ldf(g, o, f) * rsqrtf(ldf(vv, o, f) + 1e-5f);
            float sh = ldf(bb, o, f) - ldf(mm, o, f) * scv;
#pragma unroll
            for (int nt = 0; nt < 4; nt++) {
                int n = n0 + wn * 64 + nt * 16 + row;
                int b = n / NPIX, hw = n - b * NPIX;
                float val = acc[mt][nt][r] * scv + sh;
                size_t oidx = ((size_t)(b0 + b) * 384 + o) * NPIX + hw;
                if (f) ((float*)out)[oidx] = val;
                else ((bf16*)out)[oidx] = (bf16)val;
            }
        }
    }
}

// ---------------- depthwise 3x3 conv + BN, write transposed (b, hw, c) ----------------
__global__ void dwconv_kernel(const bf16* __restrict__ qb, const bf16* __restrict__ w,
                              const void* __restrict__ g, const void* __restrict__ bb,
                              const void* __restrict__ mm, const void* __restrict__ vv,
                              const int* __restrict__ flag, bf16* __restrict__ qt) {
    __shared__ bf16 tile[32][33];
    int f = *flag;
    int b = blockIdx.z;
    int c0 = blockIdx.y * 32, hw0 = blockIdx.x * 32;
    int tx = threadIdx.x, ty = threadIdx.y;
    int c = c0 + ty, hw = hw0 + tx;
    if (hw < NPIX) {
        int y = hw / 14, x = hw % 14;
        float acc = 0.f;
        const bf16* wp = w + c * 9;
        const bf16* qp = qb + ((size_t)b * 384 + c) * NPIX;
#pragma unroll
        for (int ky = 0; ky < 3; ky++) {
            int yy = y + ky - 1;
            if (yy < 0 || yy >= 14) continue;
#pragma unroll
            for (int kx = 0; kx < 3; kx++) {
                int xx = x + kx - 1;
                if (xx < 0 || xx >= 14) continue;
                acc += (float)qp[yy * 14 + xx] * (float)wp[ky * 3 + kx];
            }
        }
        float sc = ldf(g, c, f) * rsqrtf(ldf(vv, c, f) + 1e-5f);
        float sh = ldf(bb, c, f) - ldf(mm, c, f) * sc;
        tile[ty][tx] = (bf16)(acc * sc + sh);
    }
    __syncthreads();
    int hw2 = hw0 + ty, c2 = c0 + tx;
    if (hw2 < NPIX) qt[((size_t)b * NPIX + hw2) * CIN + c2] = tile[tx][ty];
}

// ---------------- bias gather: (12,196,224) fp32, pad cols = -1e30 ----------------
__global__ void bias_gather_kernel(const void* __restrict__ ab, const int* __restrict__ idx,
                                   const int* __restrict__ flag, float* __restrict__ biasf) {
    int f = *flag;
    int t = blockIdx.x * 256 + threadIdx.x;
    if (t >= NHEADS * NPIX * MPAD) return;
    int h = t / (NPIX * MPAD);
    int rem = t - h * (NPIX * MPAD);
    int n = rem / MPAD, m = rem - n * MPAD;
    biasf[t] = (m < NPIX) ? ldf(ab, h * NPIX + idx[n * NPIX + m], f) : -1e30f;
}

// ---------------- zero V pad columns (196..223) once, so 0*garbage can't NaN ----------------
__global__ void zero_vpad_kernel(bf16* __restrict__ vb, int rows) {
    int t = blockIdx.x * 256 + threadIdx.x;
    if (t >= rows * 7) return;
    int r = t / 7, c = t - r * 7;
    *(unsigned long long*)(vb + (size_t)r * MPAD + NPIX + c * 4) = 0ull;
}

// ---------------- attention per (b,h) ----------------
// Swapped-operand structure (register-resident P), V staged once into padded
// LDS, output transposed through per-wave LDS chunk for 64B-contiguous stores.
__global__ __launch_bounds__(256, 2) void attn_kernel(
    const bf16* __restrict__ qt, const bf16* __restrict__ ktp, const bf16* __restrict__ vb,
    const float* __restrict__ biasf, bf16* __restrict__ ot) {
    __shared__ bf16 Vs[128 * VSTRIDE];          // 59392 B
    __shared__ bf16 Osh[4][16 * OSTRIDE];       // 5120 B  (total 64512 <= 64KB)
    int nwg = gridDim.x * gridDim.y;
    int l = xcd_swizzle(blockIdx.y * gridDim.x + blockIdx.x, nwg);
    int h = l % NHEADS, b = l / NHEADS;
    int tid = threadIdx.x;
    int wave = tid >> 6, lane = tid & 63;
    int row = lane & 15, grp = lane >> 4;
    const float scale = 0.17677669529663687f;
    const f32x4 zf = {0.f, 0.f, 0.f, 0.f};

    // ---- stage V slice (128 x 224 bf16, contiguous 57344B) into padded LDS ----
    {
        const bf16* vsrc = vb + ((size_t)b * 1536 + h * 128) * MPAD;
#pragma unroll
        for (int it = 0; it < 14; it++) {
            int i = it * 256 + tid;               // 16B granule index, 3584 total
            int r = i / 28, gch = i - r * 28;     // 28 granules per d-row
            *(bf16x8*)(Vs + r * VSTRIDE + gch * 8) = *(const bf16x8*)(vsrc + (size_t)i * 8);
        }
    }
    __syncthreads();

    const bf16* vls = Vs + row * VSTRIDE + grp * 4;

    for (int nb = wave; nb < 13; nb += 4) {
        int n0 = nb * 16;
        int n = n0 + row;
        int nc = n > 195 ? 195 : n;

        // Q B-frag: Q[n][c = h*32 + grp*8 + j]
        bf16x8 aq = *(const bf16x8*)(qt + ((size_t)b * NPIX + nc) * CIN + h * 32 + grp * 8);

        // S^T: 14 MFMAs, K rows from global (12.5KB/head slice, L1/L2-resident)
        f32x4 sacc[14];
#pragma unroll
        for (int mt = 0; mt < 14; mt++) {
            int krow = mt * 16 + row;
            if (krow > 195) krow = 195;  // garbage rows overridden by -1e30 bias pad
            bf16x8 ak = *(const bf16x8*)(ktp + ((size_t)b * NPIX + krow) * CIN + h * 32 + grp * 8);
            sacc[mt] = __builtin_amdgcn_mfma_f32_16x16x32_bf16(ak, aq, zf, 0, 0, 0);
        }

        // bias add (vectorized via symmetry) + column max
        const float* bp = biasf + ((size_t)h * NPIX + nc) * MPAD + grp * 4;
        f32x4 mxv = {-3.4e38f, -3.4e38f, -3.4e38f, -3.4e38f};
#pragma unroll
        for (int mt = 0; mt < 14; mt++) {
            f32x4 bv = *(const f32x4*)(bp + mt * 16);
            f32x4 s = sacc[mt] * scale + bv;
            sacc[mt] = s;
            mxv = vmax4(mxv, s);
        }
        float mx = fmaxf(fmaxf(mxv[0], mxv[1]), fmaxf(mxv[2], mxv[3]));
        mx = fmaxf(mx, __shfl_xor(mx, 16));
        mx = fmaxf(mx, __shfl_xor(mx, 32));

        // exp + sum + convert to bf16 P-frags (in-register, no LDS round-trip)
        f32x4 sumv = zf;
        bf16x4 pf[14];
#pragma unroll
        for (int mt = 0; mt < 14; mt++) {
            f32x4 e;
#pragma unroll
            for (int r = 0; r < 4; r++) e[r] = __expf(sacc[mt][r] - mx);
            sumv += e;
            bf16x4 pb;
#pragma unroll
            for (int r = 0; r < 4; r++) pb[r] = (bf16)e[r];
            pf[mt] = pb;
        }
        float sum = (sumv[0] + sumv[1]) + (sumv[2] + sumv[3]);
        sum += __shfl_xor(sum, 16);
        sum += __shfl_xor(sum, 32);
        float inv = 1.f / sum;

        // PV: 112 K=16 MFMAs; V A-frags are 8B LDS reads (padded stride, ~2-way)
        f32x4 oacc[8];
#pragma unroll
        for (int dt = 0; dt < 8; dt++) oacc[dt] = zf;
#pragma unroll
        for (int mt = 0; mt < 14; mt++) {
            bf16x4 p = pf[mt];
#pragma unroll
            for (int dt = 0; dt < 8; dt++) {
                bf16x4 v4 = *(const bf16x4*)(vls + dt * 16 * VSTRIDE + mt * 16);
                oacc[dt] = mfma16(v4, p, oacc[dt]);
            }
        }

        // epilogue: normalize + ReLU, transpose 16x32-d chunks through per-wave LDS,
        // store as 64B-contiguous segments. n-guard on the store side.
        bf16* osw = Osh[wave];
        int r2 = lane >> 2, c2 = lane & 3;
        int n2 = n0 + r2;
        bf16* op = ot + ((size_t)b * NPIX + n2) * 1536 + h * 128;
#pragma unroll
        for (int dp = 0; dp < 4; dp++) {
#pragma unroll
            for (int u = 0; u < 2; u++) {
                int dt = dp * 2 + u;
                bf16x4 o4;
#pragma unroll
                for (int r = 0; r < 4; r++) {
                    float v = oacc[dt][r] * inv;
                    o4[r] = (bf16)(v > 0.f ? v : 0.f);
                }
                *(bf16x4*)(osw + row * OSTRIDE + u * 16 + grp * 4) = o4;
            }
            asm volatile("s_waitcnt lgkmcnt(0)" ::: "memory");
            if (n2 < NPIX) {
                bf16x8 ov = *(const bf16x8*)(osw + r2 * OSTRIDE + c2 * 8);
                *(bf16x8*)(op + dp * 32 + c2 * 8) = ov;
            }
            asm volatile("s_waitcnt lgkmcnt(0)" ::: "memory");
        }
    }
}

extern "C" void kernel_launch(void* const* d_in, const int* in_sizes, int n_in,
                              void* d_out, int out_size, void* d_ws, size_t ws_size,
                              hipStream_t stream) {
    const void* x      = d_in[0];
    const void* qkv_w  = d_in[1];
    const void* qkv_g  = d_in[2];
    const void* qkv_b  = d_in[3];
    const void* qkv_m  = d_in[4];
    const void* qkv_v  = d_in[5];
    const void* dw_w   = d_in[6];
    const void* dw_g   = d_in[7];
    const void* dw_b   = d_in[8];
    const void* dw_m   = d_in[9];
    const void* dw_v   = d_in[10];
    const void* proj_w = d_in[11];
    const void* proj_g = d_in[12];
    const void* proj_b = d_in[13];
    const void* proj_m = d_in[14];
    const void* proj_v = d_in[15];
    const void* ab     = d_in[16];
    const int*  idx    = (const int*)d_in[17];

    char* ws = (char*)d_ws;
    size_t off = 0;
    auto alloc = [&](size_t bytes) { void* p = ws + off; off += (bytes + 255) & ~(size_t)255; return p; };

    int*   flag = (int*)alloc(4);
    bf16*  wq   = (bf16*)alloc((size_t)2304 * 384 * 2);
    bf16*  wp   = (bf16*)alloc((size_t)384 * 1536 * 2);
    bf16*  wd   = (bf16*)alloc((size_t)384 * 9 * 2);
    float* biasf= (float*)alloc((size_t)NHEADS * NPIX * MPAD * 4);
    size_t fixed = off;

    const size_t s_xt = (size_t)NPIX * CIN;
    const size_t s_qb = (size_t)384 * NPIX;
    const size_t s_kt = (size_t)NPIX * 384;
    const size_t s_vb = (size_t)1536 * MPAD;
    const size_t s_ot = (size_t)NPIX * 1536;
    const size_t per_image = (s_xt + s_qb + s_kt + s_vb + s_ot) * 2;

    int CB = 128;
    while (CB > 32 && fixed + (size_t)CB * per_image > ws_size) CB >>= 1;

    bf16* xt  = (bf16*)alloc((size_t)CB * s_xt * 2);
    bf16* qb  = (bf16*)alloc((size_t)CB * s_qb * 2);
    bf16* ktp = (bf16*)alloc((size_t)CB * s_kt * 2);
    bf16* vb  = (bf16*)alloc((size_t)CB * s_vb * 2);
    bf16* ot  = (bf16*)alloc((size_t)CB * s_ot * 2);
    bf16* qt  = xt;  // xt dead after gemm_qkv; reuse for dwconv output

    detect_kernel<<<dim3(1), dim3(256), 0, stream>>>((const unsigned int*)x, flag);
    convert_kernel<<<dim3(256), dim3(256), 0, stream>>>(qkv_w, wq, 2304 * 384, flag);
    convert_kernel<<<dim3(256), dim3(256), 0, stream>>>(proj_w, wp, 384 * 1536, flag);
    convert_kernel<<<dim3(4), dim3(256), 0, stream>>>(dw_w, wd, 384 * 9, flag);
    int bg = (NHEADS * NPIX * MPAD + 255) / 256;
    bias_gather_kernel<<<dim3(bg), dim3(256), 0, stream>>>(ab, idx, flag, biasf);
    int vrows = CB * 1536;
    zero_vpad_kernel<<<dim3((vrows * 7 + 255) / 256), dim3(256), 0, stream>>>(vb, vrows);

    dim3 tb(32, 32);
    for (int b0 = 0; b0 < 128; b0 += CB) {
        int cb = (128 - b0 < CB) ? (128 - b0) : CB;
        int ntiles = (cb * NPIX) / 128;  // cb in {32,64,128} -> exact
        transpose_x_kernel<<<dim3(7, 12, cb), tb, 0, stream>>>(x, flag, xt, b0);
        gemm_qkv_kernel<<<dim3(18, ntiles), dim3(256), 0, stream>>>(xt, wq, qkv_g, qkv_b, qkv_m,
                                                                    qkv_v, flag, qb, ktp, vb);
        dwconv_kernel<<<dim3(7, 12, cb), tb, 0, stream>>>(qb, wd, dw_g, dw_b, dw_m, dw_v, flag, qt);
        attn_kernel<<<dim3(NHEADS, cb), dim3(256), 0, stream>>>(qt, ktp, vb, biasf, ot);
        gemm_proj_kernel<<<dim3(3, ntiles), dim3(256), 0, stream>>>(ot, wp, proj_g, proj_b, proj_m,
                                                                    proj_v, flag, d_out, b0);
    }
}

// Round 6
// 459.574 us; speedup vs baseline: 1.5165x; 1.5165x over previous
//
#include <hip/hip_runtime.h>

typedef __bf16 bf16;
typedef bf16 bf16x8 __attribute__((ext_vector_type(8)));
typedef bf16 bf16x4 __attribute__((ext_vector_type(4)));
typedef short short4v __attribute__((ext_vector_type(4)));
typedef float f32x4 __attribute__((ext_vector_type(4)));

#define NPIX 196
#define CIN 384
#define NHEADS 12
#define MPAD 224
#define VSTRIDE 232   // LDS row stride for V (bf16): ~2-way banks
#define OSTRIDE 40    // LDS row stride for store-transpose chunk
#define TSTRIDE 136   // LDS row stride for kt transpose epilogue

// flag-aware scalar load: f=1 -> fp32 data, f=0 -> bf16 data
__device__ __forceinline__ float ldf(const void* p, size_t i, int f) {
    return f ? ((const float*)p)[i] : (float)((const bf16*)p)[i];
}

// async global->LDS, 16B per lane. LDS dest must be wave-uniform base + lane*16.
__device__ __forceinline__ void gld16(const void* g, void* lds_wave_base) {
    __builtin_amdgcn_global_load_lds(
        (const __attribute__((address_space(1))) void*)(unsigned long long)g,
        (__attribute__((address_space(3))) void*)(unsigned long long)lds_wave_base,
        16, 0, 0);
}

// bijective chunked XCD swizzle (m204): consecutive hw block ids round-robin
// across 8 XCDs; remap so each XCD owns a CONTIGUOUS logical range.
__device__ __forceinline__ int xcd_swizzle(int orig, int nwg) {
    int q = nwg >> 3, r = nwg & 7;
    int xcd = orig & 7, idx = orig >> 3;
    return (xcd < r ? xcd * (q + 1) : r * (q + 1) + (xcd - r) * q) + idx;
}

// K=16 bf16 MFMA: B-frag layout (lane l: col=l&15, k=(l>>4)*4+j) matches the
// in-register P layout produced by the swapped QK^T (m = grp*4 + r).
__device__ __forceinline__ f32x4 mfma16(bf16x4 a, bf16x4 b, f32x4 c) {
#if __has_builtin(__builtin_amdgcn_mfma_f32_16x16x16bf16_1k)
    return __builtin_amdgcn_mfma_f32_16x16x16bf16_1k(
        __builtin_bit_cast(short4v, a), __builtin_bit_cast(short4v, b), c, 0, 0, 0);
#else
    asm volatile("v_mfma_f32_16x16x16_bf16 %0, %1, %2, %0" : "+v"(c) : "v"(a), "v"(b));
    return c;
#endif
}

__device__ __forceinline__ f32x4 vmax4(f32x4 a, f32x4 b) {
    f32x4 r;
    r[0] = fmaxf(a[0], b[0]);
    r[1] = fmaxf(a[1], b[1]);
    r[2] = fmaxf(a[2], b[2]);
    r[3] = fmaxf(a[3], b[3]);
    return r;
}

// ---------------- dtype detector ----------------
__global__ void detect_kernel(const unsigned int* __restrict__ x, int* __restrict__ flag) {
    __shared__ int cnt;
    if (threadIdx.x == 0) cnt = 0;
    __syncthreads();
    int c = 0;
#pragma unroll
    for (int k = 0; k < 8; k++) {
        unsigned int w = x[threadIdx.x * 8 + k];
        unsigned int e = (w >> 7) & 0xFFu;
        if (e > 200u) c++;
    }
    atomicAdd(&cnt, c);
    __syncthreads();
    if (threadIdx.x == 0) *flag = (cnt >= 16) ? 1 : 0;
}

// ---------------- canonicalize weights to bf16 ----------------
__global__ void convert_kernel(const void* __restrict__ src, bf16* __restrict__ dst, int n,
                               const int* __restrict__ flag) {
    int f = *flag;
    for (int i = blockIdx.x * 256 + threadIdx.x; i < n; i += gridDim.x * 256)
        dst[i] = (bf16)ldf(src, i, f);
}

// ---------------- transpose x: (b, c, hw) -> (b, hw, c), canonical bf16 ----------------
__global__ void transpose_x_kernel(const void* __restrict__ x, const int* __restrict__ flag,
                                   bf16* __restrict__ xt, int b0) {
    __shared__ bf16 tile[32][33];
    int f = *flag;
    int b = blockIdx.z, gb = b0 + b;
    int c0 = blockIdx.y * 32;
    int hw0 = blockIdx.x * 32;
    int tx = threadIdx.x, ty = threadIdx.y;
    int hw = hw0 + tx, c = c0 + ty;
    if (hw < NPIX) tile[ty][tx] = (bf16)ldf(x, ((size_t)gb * CIN + c) * NPIX + hw, f);
    __syncthreads();
    int hw2 = hw0 + ty, c2 = c0 + tx;
    if (hw2 < NPIX) xt[((size_t)b * NPIX + hw2) * CIN + c2] = tile[tx][ty];
}

// ---------------- 128x128 GEMM mainloop: LDS dbuf + counted vmcnt, K_STEP=32 ----------------
// Round-4-verified sync pattern (issue stage -> vmcnt(N) -> s_barrier -> ds_read
// + MFMA -> s_barrier), with K_STEP halved: LDS 64KB->32KB so 4-5 blocks/CU
// (vs 2) cover stage latency across barriers. Staging: 512 granules of 16B per
// matrix per step, granule g = p*256+tid -> row g>>2, slot g&3; source chunk
// (lane&3)^(row&3) (XOR swizzle, 4 chunks/row => ~2-way banks on read, free).
// smem layout: As dbuf [2][128*32], Bs dbuf [2][128*32] (32768 bf16 total).
template <int K>
__device__ __forceinline__ void gemm_tile32(const bf16* __restrict__ A, const bf16* __restrict__ B,
                                            bf16* smem, f32x4 acc[4][4]) {
    int tid = threadIdx.x;
    int wave = tid >> 6, lane = tid & 63;
    int wm = wave >> 1, wn = wave & 1;
    int row = lane & 15, grp = lane >> 4;
    int sr = lane >> 2;                 // 0..15: staged row within wave's 16-row group
    int scg = (lane & 3) ^ (sr & 3);    // swizzled source chunk
    const int BUF = 128 * 32;
    bf16* As = smem;
    bf16* Bs = smem + 2 * BUF;
    const bf16* Ag = A + (size_t)(wave * 16 + sr) * K + scg * 8;
    const bf16* Bg = B + (size_t)(wave * 16 + sr) * K + scg * 8;
    // prologue: stage kb=0 into buffer 0 (4 outstanding vmem ops/wave)
#pragma unroll
    for (int p = 0; p < 2; p++) {
        gld16(Ag + (size_t)(p * 64) * K, As + (p * 256 + wave * 64) * 8);
        gld16(Bg + (size_t)(p * 64) * K, Bs + (p * 256 + wave * 64) * 8);
    }
    int cur = 0;
#pragma unroll 1
    for (int kb = 0; kb < K; kb += 32) {
        if (kb + 32 < K) {  // prefetch next K-step into the other buffer
            bf16* Asn = As + (cur ^ 1) * BUF;
            bf16* Bsn = Bs + (cur ^ 1) * BUF;
#pragma unroll
            for (int p = 0; p < 2; p++) {
                gld16(Ag + (size_t)(p * 64) * K + kb + 32, Asn + (p * 256 + wave * 64) * 8);
                gld16(Bg + (size_t)(p * 64) * K + kb + 32, Bsn + (p * 256 + wave * 64) * 8);
            }
            __builtin_amdgcn_sched_barrier(0);
            asm volatile("s_waitcnt vmcnt(4)" ::: "memory");  // drain PREVIOUS tile only
        } else {
            __builtin_amdgcn_sched_barrier(0);
            asm volatile("s_waitcnt vmcnt(0)" ::: "memory");
        }
        __builtin_amdgcn_s_barrier();
        __builtin_amdgcn_sched_barrier(0);
        const bf16* Asc = As + cur * BUF;
        const bf16* Bsc = Bs + cur * BUF;
        bf16x8 af[4], bfr[4];
#pragma unroll
        for (int t = 0; t < 4; t++) {
            int ra = wm * 64 + t * 16 + row;
            af[t] = *(const bf16x8*)(Asc + ra * 32 + ((grp ^ (ra & 3)) * 8));
            int rb = wn * 64 + t * 16 + row;
            bfr[t] = *(const bf16x8*)(Bsc + rb * 32 + ((grp ^ (rb & 3)) * 8));
        }
#pragma unroll
        for (int mt = 0; mt < 4; mt++)
#pragma unroll
            for (int nt = 0; nt < 4; nt++)
                acc[mt][nt] =
                    __builtin_amdgcn_mfma_f32_16x16x32_bf16(af[mt], bfr[nt], acc[mt][nt], 0, 0, 0);
        __builtin_amdgcn_sched_barrier(0);
        __builtin_amdgcn_s_barrier();   // all waves done reading cur before overwrite
        cur ^= 1;
    }
    __builtin_amdgcn_sched_barrier(0);
}

// ---------------- QKV GEMM + BN, routed outputs ----------------
__global__ __launch_bounds__(256) void gemm_qkv_kernel(
    const bf16* __restrict__ xt, const bf16* __restrict__ w,
    const void* __restrict__ g, const void* __restrict__ bb,
    const void* __restrict__ mm, const void* __restrict__ vv, const int* __restrict__ flag,
    bf16* __restrict__ qb, bf16* __restrict__ kt, bf16* __restrict__ vb) {
    // 34816B: gemm dbuf (32768 bf16 = first 32KB) overlaid with kt transpose buf
    __shared__ bf16 smem[128 * TSTRIDE];
    f32x4 acc[4][4];
#pragma unroll
    for (int i = 0; i < 4; i++)
#pragma unroll
        for (int j = 0; j < 4; j++) acc[i][j] = (f32x4){0.f, 0.f, 0.f, 0.f};
    // XCD swizzle: all 18 m-tiles of contiguous n-tile ranges land on one XCD,
    // so the shared 98KB B-tile is fetched from HBM once and staged from L2.
    int nwg = gridDim.x * gridDim.y;
    int l = xcd_swizzle(blockIdx.y * gridDim.x + blockIdx.x, nwg);
    int m0 = (l % gridDim.x) * 128, n0 = (l / gridDim.x) * 128;
    gemm_tile32<CIN>(w + (size_t)m0 * CIN, xt + (size_t)n0 * CIN, smem, acc);
    int f = *flag;
    int tid = threadIdx.x;
    int wave = tid >> 6, lane = tid & 63;
    int wm = wave >> 1, wn = wave & 1, row = lane & 15, grp = lane >> 4;
    if (m0 >= 384 && m0 < 768) {
        // k-part: direct stores scatter 64 lines/wave-store (row stride 768B).
        // Transpose through LDS (overlaid on freed smem) -> 256B-contiguous rows.
        bf16* tbuf = smem;  // [128][TSTRIDE]
#pragma unroll
        for (int mt = 0; mt < 4; mt++) {
#pragma unroll
            for (int r = 0; r < 4; r++) {
                int ol = wm * 64 + mt * 16 + grp * 4 + r;
                int o = m0 + ol;
                float scv = ldf(g, o, f) * rsqrtf(ldf(vv, o, f) + 1e-5f);
                float sh = ldf(bb, o, f) - ldf(mm, o, f) * scv;
#pragma unroll
                for (int nt = 0; nt < 4; nt++) {
                    int nl = wn * 64 + nt * 16 + row;
                    tbuf[nl * TSTRIDE + ol] = (bf16)(acc[mt][nt][r] * scv + sh);
                }
            }
        }
        __syncthreads();
        // kt row address is LINEAR in n: (b*196+hw)*384 = n*384.
#pragma unroll
        for (int it = 0; it < 8; it++) {
            int g2 = it * 256 + tid;            // 2048 granules of 16B
            int nl = g2 >> 4, ch = g2 & 15;
            *(bf16x8*)(kt + (size_t)(n0 + nl) * CIN + (m0 - 384) + ch * 8) =
                *(const bf16x8*)(tbuf + nl * TSTRIDE + ch * 8);
        }
    } else {
#pragma unroll
        for (int mt = 0; mt < 4; mt++) {
#pragma unroll
            for (int r = 0; r < 4; r++) {
                int o = m0 + wm * 64 + mt * 16 + grp * 4 + r;
                float scv = ldf(g, o, f) * rsqrtf(ldf(vv, o, f) + 1e-5f);
                float sh = ldf(bb, o, f) - ldf(mm, o, f) * scv;
#pragma unroll
                for (int nt = 0; nt < 4; nt++) {
                    int n = n0 + wn * 64 + nt * 16 + row;
                    int b = n / NPIX, hw = n - b * NPIX;
                    float val = acc[mt][nt][r] * scv + sh;
                    bf16 bv = (bf16)val;
                    if (o < 384) {
                        qb[((size_t)b * 384 + o) * NPIX + hw] = bv;
                    } else {
                        vb[((size_t)b * 1536 + (o - 768)) * MPAD + hw] = bv;
                    }
                }
            }
        }
    }
}

// ---------------- proj GEMM + BN -> output ----------------
__global__ __launch_bounds__(256) void gemm_proj_kernel(
    const bf16* __restrict__ ot, const bf16* __restrict__ w,
    const void* __restrict__ g, const void* __restrict__ bb,
    const void* __restrict__ mm, const void* __restrict__ vv, const int* __restrict__ flag,
    void* __restrict__ out, int b0) {
    __shared__ bf16 smem[4 * 128 * 32];   // 32KB -> 5 blocks/CU
    f32x4 acc[4][4];
#pragma unroll
    for (int i = 0; i < 4; i++)
#pragma unroll
        for (int j = 0; j < 4; j++) acc[i][j] = (f32x4){0.f, 0.f, 0.f, 0.f};
    int nwg = gridDim.x * gridDim.y;
    int l = xcd_swizzle(blockIdx.y * gridDim.x + blockIdx.x, nwg);
    int m0 = (l % gridDim.x) * 128, n0 = (l / gridDim.x) * 128;
    gemm_tile32<1536>(w + (size_t)m0 * 1536, ot + (size_t)n0 * 1536, smem, acc);
    int f = *flag;
    int wave = threadIdx.x >> 6, lane = threadIdx.x & 63;
    int wm = wave >> 1, wn = wave & 1, row = lane & 15, grp = lane >> 4;
#pragma unroll
    for (int mt = 0; mt < 4; mt++) {
#pragma unroll
        for (int r = 0; r < 4; r++) {
            int o = m0 + wm * 64 + mt * 16 + grp * 4 + r;
            float scv = ldf(g, o, f) * rsqrtf(ldf(vv, o, f) + 1e-5f);
            float sh = ldf(bb, o, f) - ldf(mm, o, f) * scv;
#pragma unroll
            for (int nt = 0; nt < 4; nt++) {
                int n = n0 + wn * 64 + nt * 16 + row;
                int b = n / NPIX, hw = n - b * NPIX;
                float val = acc[mt][nt][r] * scv + sh;
                size_t oidx = ((size_t)(b0 + b) * 384 + o) * NPIX + hw;
                if (f) ((float*)out)[oidx] = val;
                else ((bf16*)out)[oidx] = (bf16)val;
            }
        }
    }
}

// ---------------- depthwise 3x3 conv + BN, write transposed (b, hw, c) ----------------
__global__ void dwconv_kernel(const bf16* __restrict__ qb, const bf16* __restrict__ w,
                              const void* __restrict__ g, const void* __restrict__ bb,
                              const void* __restrict__ mm, const void* __restrict__ vv,
                              const int* __restrict__ flag, bf16* __restrict__ qt) {
    __shared__ bf16 tile[32][33];
    int f = *flag;
    int b = blockIdx.z;
    int c0 = blockIdx.y * 32, hw0 = blockIdx.x * 32;
    int tx = threadIdx.x, ty = threadIdx.y;
    int c = c0 + ty, hw = hw0 + tx;
    if (hw < NPIX) {
        int y = hw / 14, x = hw % 14;
        float acc = 0.f;
        const bf16* wp = w + c * 9;
        const bf16* qp = qb + ((size_t)b * 384 + c) * NPIX;
#pragma unroll
        for (int ky = 0; ky < 3; ky++) {
            int yy = y + ky - 1;
            if (yy < 0 || yy >= 14) continue;
#pragma unroll
            for (int kx = 0; kx < 3; kx++) {
                int xx = x + kx - 1;
                if (xx < 0 || xx >= 14) continue;
                acc += (float)qp[yy * 14 + xx] * (float)wp[ky * 3 + kx];
            }
        }
        float sc = ldf(g, c, f) * rsqrtf(ldf(vv, c, f) + 1e-5f);
        float sh = ldf(bb, c, f) - ldf(mm, c, f) * sc;
        tile[ty][tx] = (bf16)(acc * sc + sh);
    }
    __syncthreads();
    int hw2 = hw0 + ty, c2 = c0 + tx;
    if (hw2 < NPIX) qt[((size_t)b * NPIX + hw2) * CIN + c2] = tile[tx][ty];
}

// ---------------- bias gather: (12,196,224) fp32, pad cols = -1e30 ----------------
__global__ void bias_gather_kernel(const void* __restrict__ ab, const int* __restrict__ idx,
                                   const int* __restrict__ flag, float* __restrict__ biasf) {
    int f = *flag;
    int t = blockIdx.x * 256 + threadIdx.x;
    if (t >= NHEADS * NPIX * MPAD) return;
    int h = t / (NPIX * MPAD);
    int rem = t - h * (NPIX * MPAD);
    int n = rem / MPAD, m = rem - n * MPAD;
    biasf[t] = (m < NPIX) ? ldf(ab, h * NPIX + idx[n * NPIX + m], f) : -1e30f;
}

// ---------------- zero V pad columns (196..223) once, so 0*garbage can't NaN ----------------
__global__ void zero_vpad_kernel(bf16* __restrict__ vb, int rows) {
    int t = blockIdx.x * 256 + threadIdx.x;
    if (t >= rows * 7) return;
    int r = t / 7, c = t - r * 7;
    *(unsigned long long*)(vb + (size_t)r * MPAD + NPIX + c * 4) = 0ull;
}

// ---------------- attention per (b,h) ----------------
// Swapped-operand structure (register-resident P), V staged once into padded
// LDS, output transposed through per-wave LDS chunk for 64B-contiguous stores.
__global__ __launch_bounds__(256, 2) void attn_kernel(
    const bf16* __restrict__ qt, const bf16* __restrict__ ktp, const bf16* __restrict__ vb,
    const float* __restrict__ biasf, bf16* __restrict__ ot) {
    __shared__ bf16 Vs[128 * VSTRIDE];          // 59392 B
    __shared__ bf16 Osh[4][16 * OSTRIDE];       // 5120 B  (total 64512 <= 64KB)
    int nwg = gridDim.x * gridDim.y;
    int l = xcd_swizzle(blockIdx.y * gridDim.x + blockIdx.x, nwg);
    int h = l % NHEADS, b = l / NHEADS;
    int tid = threadIdx.x;
    int wave = tid >> 6, lane = tid & 63;
    int row = lane & 15, grp = lane >> 4;
    const float scale = 0.17677669529663687f;
    const f32x4 zf = {0.f, 0.f, 0.f, 0.f};

    // ---- stage V slice (128 x 224 bf16, contiguous 57344B) into padded LDS ----
    {
        const bf16* vsrc = vb + ((size_t)b * 1536 + h * 128) * MPAD;
#pragma unroll
        for (int it = 0; it < 14; it++) {
            int i = it * 256 + tid;               // 16B granule index, 3584 total
            int r = i / 28, gch = i - r * 28;     // 28 granules per d-row
            *(bf16x8*)(Vs + r * VSTRIDE + gch * 8) = *(const bf16x8*)(vsrc + (size_t)i * 8);
        }
    }
    __syncthreads();

    const bf16* vls = Vs + row * VSTRIDE + grp * 4;

    for (int nb = wave; nb < 13; nb += 4) {
        int n0 = nb * 16;
        int n = n0 + row;
        int nc = n > 195 ? 195 : n;

        // Q B-frag: Q[n][c = h*32 + grp*8 + j]
        bf16x8 aq = *(const bf16x8*)(qt + ((size_t)b * NPIX + nc) * CIN + h * 32 + grp * 8);

        // S^T: 14 MFMAs, K rows from global (12.5KB/head slice, L1/L2-resident)
        f32x4 sacc[14];
#pragma unroll
        for (int mt = 0; mt < 14; mt++) {
            int krow = mt * 16 + row;
            if (krow > 195) krow = 195;  // garbage rows overridden by -1e30 bias pad
            bf16x8 ak = *(const bf16x8*)(ktp + ((size_t)b * NPIX + krow) * CIN + h * 32 + grp * 8);
            sacc[mt] = __builtin_amdgcn_mfma_f32_16x16x32_bf16(ak, aq, zf, 0, 0, 0);
        }

        // bias add (vectorized via symmetry) + column max
        const float* bp = biasf + ((size_t)h * NPIX + nc) * MPAD + grp * 4;
        f32x4 mxv = {-3.4e38f, -3.4e38f, -3.4e38f, -3.4e38f};
#pragma unroll
        for (int mt = 0; mt < 14; mt++) {
            f32x4 bv = *(const f32x4*)(bp + mt * 16);
            f32x4 s = sacc[mt] * scale + bv;
            sacc[mt] = s;
            mxv = vmax4(mxv, s);
        }
        float mx = fmaxf(fmaxf(mxv[0], mxv[1]), fmaxf(mxv[2], mxv[3]));
        mx = fmaxf(mx, __shfl_xor(mx, 16));
        mx = fmaxf(mx, __shfl_xor(mx, 32));

        // exp + sum + convert to bf16 P-frags (in-register, no LDS round-trip)
        f32x4 sumv = zf;
        bf16x4 pf[14];
#pragma unroll
        for (int mt = 0; mt < 14; mt++) {
            f32x4 e;
#pragma unroll
            for (int r = 0; r < 4; r++) e[r] = __expf(sacc[mt][r] - mx);
            sumv += e;
            bf16x4 pb;
#pragma unroll
            for (int r = 0; r < 4; r++) pb[r] = (bf16)e[r];
            pf[mt] = pb;
        }
        float sum = (sumv[0] + sumv[1]) + (sumv[2] + sumv[3]);
        sum += __shfl_xor(sum, 16);
        sum += __shfl_xor(sum, 32);
        float inv = 1.f / sum;

        // PV: 112 K=16 MFMAs; V A-frags are 8B LDS reads (padded stride, ~2-way)
        f32x4 oacc[8];
#pragma unroll
        for (int dt = 0; dt < 8; dt++) oacc[dt] = zf;
#pragma unroll
        for (int mt = 0; mt < 14; mt++) {
            bf16x4 p = pf[mt];
#pragma unroll
            for (int dt = 0; dt < 8; dt++) {
                bf16x4 v4 = *(const bf16x4*)(vls + dt * 16 * VSTRIDE + mt * 16);
                oacc[dt] = mfma16(v4, p, oacc[dt]);
            }
        }

        // epilogue: normalize + ReLU, transpose 16x32-d chunks through per-wave LDS,
        // store as 64B-contiguous segments. n-guard on the store side.
        bf16* osw = Osh[wave];
        int r2 = lane >> 2, c2 = lane & 3;
        int n2 = n0 + r2;
        bf16* op = ot + ((size_t)b * NPIX + n2) * 1536 + h * 128;
#pragma unroll
        for (int dp = 0; dp < 4; dp++) {
#pragma unroll
            for (int u = 0; u < 2; u++) {
                int dt = dp * 2 + u;
                bf16x4 o4;
#pragma unroll
                for (int r = 0; r < 4; r++) {
                    float v = oacc[dt][r] * inv;
                    o4[r] = (bf16)(v > 0.f ? v : 0.f);
                }
                *(bf16x4*)(osw + row * OSTRIDE + u * 16 + grp * 4) = o4;
            }
            asm volatile("s_waitcnt lgkmcnt(0)" ::: "memory");
            if (n2 < NPIX) {
                bf16x8 ov = *(const bf16x8*)(osw + r2 * OSTRIDE + c2 * 8);
                *(bf16x8*)(op + dp * 32 + c2 * 8) = ov;
            }
            asm volatile("s_waitcnt lgkmcnt(0)" ::: "memory");
        }
    }
}

extern "C" void kernel_launch(void* const* d_in, const int* in_sizes, int n_in,
                              void* d_out, int out_size, void* d_ws, size_t ws_size,
                              hipStream_t stream) {
    const void* x      = d_in[0];
    const void* qkv_w  = d_in[1];
    const void* qkv_g  = d_in[2];
    const void* qkv_b  = d_in[3];
    const void* qkv_m  = d_in[4];
    const void* qkv_v  = d_in[5];
    const void* dw_w   = d_in[6];
    const void* dw_g   = d_in[7];
    const void* dw_b   = d_in[8];
    const void* dw_m   = d_in[9];
    const void* dw_v   = d_in[10];
    const void* proj_w = d_in[11];
    const void* proj_g = d_in[12];
    const void* proj_b = d_in[13];
    const void* proj_m = d_in[14];
    const void* proj_v = d_in[15];
    const void* ab     = d_in[16];
    const int*  idx    = (const int*)d_in[17];

    char* ws = (char*)d_ws;
    size_t off = 0;
    auto alloc = [&](size_t bytes) { void* p = ws + off; off += (bytes + 255) & ~(size_t)255; return p; };

    int*   flag = (int*)alloc(4);
    bf16*  wq   = (bf16*)alloc((size_t)2304 * 384 * 2);
    bf16*  wp   = (bf16*)alloc((size_t)384 * 1536 * 2);
    bf16*  wd   = (bf16*)alloc((size_t)384 * 9 * 2);
    float* biasf= (float*)alloc((size_t)NHEADS * NPIX * MPAD * 4);
    size_t fixed = off;

    const size_t s_xt = (size_t)NPIX * CIN;
    const size_t s_qb = (size_t)384 * NPIX;
    const size_t s_kt = (size_t)NPIX * 384;
    const size_t s_vb = (size_t)1536 * MPAD;
    const size_t s_ot = (size_t)NPIX * 1536;
    const size_t per_image = (s_xt + s_qb + s_kt + s_vb + s_ot) * 2;

    int CB = 128;
    while (CB > 32 && fixed + (size_t)CB * per_image > ws_size) CB >>= 1;

    bf16* xt  = (bf16*)alloc((size_t)CB * s_xt * 2);
    bf16* qb  = (bf16*)alloc((size_t)CB * s_qb * 2);
    bf16* ktp = (bf16*)alloc((size_t)CB * s_kt * 2);
    bf16* vb  = (bf16*)alloc((size_t)CB * s_vb * 2);
    bf16* ot  = (bf16*)alloc((size_t)CB * s_ot * 2);
    bf16* qt  = xt;  // xt dead after gemm_qkv; reuse for dwconv output

    detect_kernel<<<dim3(1), dim3(256), 0, stream>>>((const unsigned int*)x, flag);
    convert_kernel<<<dim3(256), dim3(256), 0, stream>>>(qkv_w, wq, 2304 * 384, flag);
    convert_kernel<<<dim3(256), dim3(256), 0, stream>>>(proj_w, wp, 384 * 1536, flag);
    convert_kernel<<<dim3(4), dim3(256), 0, stream>>>(dw_w, wd, 384 * 9, flag);
    int bg = (NHEADS * NPIX * MPAD + 255) / 256;
    bias_gather_kernel<<<dim3(bg), dim3(256), 0, stream>>>(ab, idx, flag, biasf);
    int vrows = CB * 1536;
    zero_vpad_kernel<<<dim3((vrows * 7 + 255) / 256), dim3(256), 0, stream>>>(vb, vrows);

    dim3 tb(32, 32);
    for (int b0 = 0; b0 < 128; b0 += CB) {
        int cb = (128 - b0 < CB) ? (128 - b0) : CB;
        int ntiles = (cb * NPIX) / 128;  // cb in {32,64,128} -> exact
        transpose_x_kernel<<<dim3(7, 12, cb), tb, 0, stream>>>(x, flag, xt, b0);
        gemm_qkv_kernel<<<dim3(18, ntiles), dim3(256), 0, stream>>>(xt, wq, qkv_g, qkv_b, qkv_m,
                                                                    qkv_v, flag, qb, ktp, vb);
        dwconv_kernel<<<dim3(7, 12, cb), tb, 0, stream>>>(qb, wd, dw_g, dw_b, dw_m, dw_v, flag, qt);
        attn_kernel<<<dim3(NHEADS, cb), dim3(256), 0, stream>>>(qt, ktp, vb, biasf, ot);
        gemm_proj_kernel<<<dim3(3, ntiles), dim3(256), 0, stream>>>(ot, wp, proj_g, proj_b, proj_m,
                                                                    proj_v, flag, d_out, b0);
    }
}

// Round 7
// 433.889 us; speedup vs baseline: 1.6062x; 1.0592x over previous
//
#include <hip/hip_runtime.h>

typedef __bf16 bf16;
typedef bf16 bf16x8 __attribute__((ext_vector_type(8)));
typedef bf16 bf16x4 __attribute__((ext_vector_type(4)));
typedef short short4v __attribute__((ext_vector_type(4)));
typedef float f32x4 __attribute__((ext_vector_type(4)));

#define NPIX 196
#define CIN 384
#define NHEADS 12
#define MPAD 224
#define VSTRIDE 232   // LDS row stride for V (bf16): ~2-way banks
#define OSTRIDE 40    // LDS row stride for store-transpose chunk
#define TSTRIDE 136   // LDS row stride for kt transpose epilogue

#define N_WQ (2304 * 384)
#define N_WP (384 * 1536)
#define N_WD (384 * 9)
#define N_BI (NHEADS * NPIX * MPAD)

// flag-aware scalar load: f=1 -> fp32 data, f=0 -> bf16 data
__device__ __forceinline__ float ldf(const void* p, size_t i, int f) {
    return f ? ((const float*)p)[i] : (float)((const bf16*)p)[i];
}

// async global->LDS, 16B per lane. LDS dest must be wave-uniform base + lane*16.
__device__ __forceinline__ void gld16(const void* g, void* lds_wave_base) {
    __builtin_amdgcn_global_load_lds(
        (const __attribute__((address_space(1))) void*)(unsigned long long)g,
        (__attribute__((address_space(3))) void*)(unsigned long long)lds_wave_base,
        16, 0, 0);
}

// bijective chunked XCD swizzle (m204): consecutive hw block ids round-robin
// across 8 XCDs; remap so each XCD owns a CONTIGUOUS logical range.
__device__ __forceinline__ int xcd_swizzle(int orig, int nwg) {
    int q = nwg >> 3, r = nwg & 7;
    int xcd = orig & 7, idx = orig >> 3;
    return (xcd < r ? xcd * (q + 1) : r * (q + 1) + (xcd - r) * q) + idx;
}

// K=16 bf16 MFMA: B-frag layout (lane l: col=l&15, k=(l>>4)*4+j) matches the
// in-register P layout produced by the swapped QK^T (m = grp*4 + r).
__device__ __forceinline__ f32x4 mfma16(bf16x4 a, bf16x4 b, f32x4 c) {
#if __has_builtin(__builtin_amdgcn_mfma_f32_16x16x16bf16_1k)
    return __builtin_amdgcn_mfma_f32_16x16x16bf16_1k(
        __builtin_bit_cast(short4v, a), __builtin_bit_cast(short4v, b), c, 0, 0, 0);
#else
    asm volatile("v_mfma_f32_16x16x16_bf16 %0, %1, %2, %0" : "+v"(c) : "v"(a), "v"(b));
    return c;
#endif
}

__device__ __forceinline__ f32x4 vmax4(f32x4 a, f32x4 b) {
    f32x4 r;
    r[0] = fmaxf(a[0], b[0]);
    r[1] = fmaxf(a[1], b[1]);
    r[2] = fmaxf(a[2], b[2]);
    r[3] = fmaxf(a[3], b[3]);
    return r;
}

// ---------------- dtype detector ----------------
__global__ void detect_kernel(const unsigned int* __restrict__ x, int* __restrict__ flag) {
    __shared__ int cnt;
    if (threadIdx.x == 0) cnt = 0;
    __syncthreads();
    int c = 0;
#pragma unroll
    for (int k = 0; k < 8; k++) {
        unsigned int w = x[threadIdx.x * 8 + k];
        unsigned int e = (w >> 7) & 0xFFu;
        if (e > 200u) c++;
    }
    atomicAdd(&cnt, c);
    __syncthreads();
    if (threadIdx.x == 0) *flag = (cnt >= 16) ? 1 : 0;
}

// ---------------- fused prep: weight converts + bias gather + V-pad zero ----------------
// One launch instead of five (cuts serial launch gaps).
__global__ void prep_kernel(const void* __restrict__ qkv_w, const void* __restrict__ proj_w,
                            const void* __restrict__ dw_w, const void* __restrict__ ab,
                            const int* __restrict__ idx, const int* __restrict__ flag,
                            bf16* __restrict__ wq, bf16* __restrict__ wp, bf16* __restrict__ wd,
                            float* __restrict__ biasf, bf16* __restrict__ vb, int nvpad) {
    int f = *flag;
    long t = (long)blockIdx.x * 256 + threadIdx.x;
    if (t < N_WQ) { wq[t] = (bf16)ldf(qkv_w, t, f); return; }
    t -= N_WQ;
    if (t < N_WP) { wp[t] = (bf16)ldf(proj_w, t, f); return; }
    t -= N_WP;
    if (t < N_WD) { wd[t] = (bf16)ldf(dw_w, t, f); return; }
    t -= N_WD;
    if (t < N_BI) {
        // bias_idxs is symmetric (|dy|,|dx|): biasf[h][n][m] == bias[m][n]; pad m -> -1e30
        int h = (int)(t / (NPIX * MPAD));
        int rem = (int)(t - (long)h * (NPIX * MPAD));
        int n = rem / MPAD, m = rem - n * MPAD;
        biasf[t] = (m < NPIX) ? ldf(ab, h * NPIX + idx[n * NPIX + m], f) : -1e30f;
        return;
    }
    t -= N_BI;
    if (t < nvpad) {
        long r = t / 7, c = t - r * 7;
        *(unsigned long long*)(vb + r * MPAD + NPIX + c * 4) = 0ull;  // 0*garbage can't NaN
    }
}

// ---------------- transpose x: (b, c, hw) -> (b, hw, c), canonical bf16 ----------------
__global__ void transpose_x_kernel(const void* __restrict__ x, const int* __restrict__ flag,
                                   bf16* __restrict__ xt, int b0) {
    __shared__ bf16 tile[32][33];
    int f = *flag;
    int b = blockIdx.z, gb = b0 + b;
    int c0 = blockIdx.y * 32;
    int hw0 = blockIdx.x * 32;
    int tx = threadIdx.x, ty = threadIdx.y;
    int hw = hw0 + tx, c = c0 + ty;
    if (hw < NPIX) tile[ty][tx] = (bf16)ldf(x, ((size_t)gb * CIN + c) * NPIX + hw, f);
    __syncthreads();
    int hw2 = hw0 + ty, c2 = c0 + tx;
    if (hw2 < NPIX) xt[((size_t)b * NPIX + hw2) * CIN + c2] = tile[tx][ty];
}

// ---------------- 128x128 GEMM mainloop: triple-buffer K_STEP=32, 1 barrier/step ----------------
// Per iter: vmcnt(4) (drain step s's 4 loads; step s+1 stays in flight) -> s_barrier
// -> issue stage for step s+2 (safe: barrier guarantees buf (s-1)%3 fully consumed)
// -> 8 ds_read_b128 -> 16 MFMA. Barrier count per K == round-4 loop, but LDS
// 48KB -> 3 blocks/CU (12 waves) and prefetch depth 2 compute phases.
// XOR swizzle key (r>>1)&3: rows r,r+8 alias (2-way = free); r6's (r&3) was 4-way.
template <int K>
__device__ __forceinline__ void gemm_tile3(const bf16* __restrict__ A, const bf16* __restrict__ B,
                                           bf16* smem, f32x4 acc[4][4]) {
    constexpr int NS = K / 32;
    const int BUF = 128 * 32;
    int tid = threadIdx.x;
    int wave = tid >> 6, lane = tid & 63;
    int wm = wave >> 1, wn = wave & 1;
    int row = lane & 15, grp = lane >> 4;
    int sr = lane >> 2;                       // row within 16-row staging group
    int scg = (lane & 3) ^ ((sr >> 1) & 3);   // source chunk, 2-way-free swizzle
    bf16* As = smem;                          // [3][BUF]
    bf16* Bs = smem + 3 * BUF;                // [3][BUF]
    const bf16* Ag = A + (size_t)(wave * 16 + sr) * K + scg * 8;
    const bf16* Bg = B + (size_t)(wave * 16 + sr) * K + scg * 8;
    int dbase = (wave * 64) * 8;              // + p*2048
    int rs = (grp ^ ((row >> 1) & 3)) * 8;    // read slot (static: (ra>>1)&3 == (row>>1)&3)

#define STAGE3(s, bi)                                                            \
    {                                                                            \
        bf16* Ad = As + (bi) * BUF;                                              \
        bf16* Bd = Bs + (bi) * BUF;                                              \
        _Pragma("unroll") for (int p = 0; p < 2; p++) {                          \
            gld16(Ag + (size_t)(p * 64) * K + (s) * 32, Ad + p * 2048 + dbase);  \
            gld16(Bg + (size_t)(p * 64) * K + (s) * 32, Bd + p * 2048 + dbase);  \
        }                                                                        \
    }

    STAGE3(0, 0);
    STAGE3(1, 1);
    int cb = 0, nb = 2;
#pragma unroll 1
    for (int s = 0; s < NS; s++) {
        __builtin_amdgcn_sched_barrier(0);
        if (s < NS - 1) {
            asm volatile("s_waitcnt vmcnt(4)" ::: "memory");
        } else {
            asm volatile("s_waitcnt vmcnt(0)" ::: "memory");
        }
        __builtin_amdgcn_s_barrier();
        __builtin_amdgcn_sched_barrier(0);
        if (s + 2 < NS) {
            STAGE3(s + 2, nb);
        }
        const bf16* Asc = As + cb * BUF;
        const bf16* Bsc = Bs + cb * BUF;
        bf16x8 af[4], bfr[4];
#pragma unroll
        for (int t = 0; t < 4; t++) {
            af[t] = *(const bf16x8*)(Asc + (wm * 64 + t * 16 + row) * 32 + rs);
            bfr[t] = *(const bf16x8*)(Bsc + (wn * 64 + t * 16 + row) * 32 + rs);
        }
#pragma unroll
        for (int mt = 0; mt < 4; mt++)
#pragma unroll
            for (int nt = 0; nt < 4; nt++)
                acc[mt][nt] =
                    __builtin_amdgcn_mfma_f32_16x16x32_bf16(af[mt], bfr[nt], acc[mt][nt], 0, 0, 0);
        cb = (cb == 2) ? 0 : cb + 1;
        nb = (nb == 2) ? 0 : nb + 1;
    }
#undef STAGE3
    __builtin_amdgcn_sched_barrier(0);
    __builtin_amdgcn_s_barrier();   // epilogue may overlay smem
}

// ---------------- QKV GEMM + BN, routed outputs ----------------
__global__ __launch_bounds__(256) void gemm_qkv_kernel(
    const bf16* __restrict__ xt, const bf16* __restrict__ w,
    const void* __restrict__ g, const void* __restrict__ bb,
    const void* __restrict__ mm, const void* __restrict__ vv, const int* __restrict__ flag,
    bf16* __restrict__ qb, bf16* __restrict__ kt, bf16* __restrict__ vb) {
    // 49152B: 3-buf A + 3-buf B; reused as kt transpose buf (34816B) after loop
    __shared__ bf16 smem[6 * 128 * 32];
    f32x4 acc[4][4];
#pragma unroll
    for (int i = 0; i < 4; i++)
#pragma unroll
        for (int j = 0; j < 4; j++) acc[i][j] = (f32x4){0.f, 0.f, 0.f, 0.f};
    // XCD swizzle: all 18 m-tiles of contiguous n-tile ranges land on one XCD,
    // so the shared 98KB B-tile is fetched from HBM once and staged from L2.
    int nwg = gridDim.x * gridDim.y;
    int l = xcd_swizzle(blockIdx.y * gridDim.x + blockIdx.x, nwg);
    int m0 = (l % gridDim.x) * 128, n0 = (l / gridDim.x) * 128;
    gemm_tile3<CIN>(w + (size_t)m0 * CIN, xt + (size_t)n0 * CIN, smem, acc);
    int f = *flag;
    int tid = threadIdx.x;
    int wave = tid >> 6, lane = tid & 63;
    int wm = wave >> 1, wn = wave & 1, row = lane & 15, grp = lane >> 4;
    if (m0 >= 384 && m0 < 768) {
        // k-part: direct stores scatter 64 lines/wave-store (row stride 768B).
        // Transpose through LDS (overlaid on freed smem) -> 256B-contiguous rows.
        bf16* tbuf = smem;  // [128][TSTRIDE]
#pragma unroll
        for (int mt = 0; mt < 4; mt++) {
#pragma unroll
            for (int r = 0; r < 4; r++) {
                int ol = wm * 64 + mt * 16 + grp * 4 + r;
                int o = m0 + ol;
                float scv = ldf(g, o, f) * rsqrtf(ldf(vv, o, f) + 1e-5f);
                float sh = ldf(bb, o, f) - ldf(mm, o, f) * scv;
#pragma unroll
                for (int nt = 0; nt < 4; nt++) {
                    int nl = wn * 64 + nt * 16 + row;
                    tbuf[nl * TSTRIDE + ol] = (bf16)(acc[mt][nt][r] * scv + sh);
                }
            }
        }
        __syncthreads();
        // kt row address is LINEAR in n: (b*196+hw)*384 = n*384.
#pragma unroll
        for (int it = 0; it < 8; it++) {
            int g2 = it * 256 + tid;            // 2048 granules of 16B
            int nl = g2 >> 4, ch = g2 & 15;
            *(bf16x8*)(kt + (size_t)(n0 + nl) * CIN + (m0 - 384) + ch * 8) =
                *(const bf16x8*)(tbuf + nl * TSTRIDE + ch * 8);
        }
    } else {
#pragma unroll
        for (int mt = 0; mt < 4; mt++) {
#pragma unroll
            for (int r = 0; r < 4; r++) {
                int o = m0 + wm * 64 + mt * 16 + grp * 4 + r;
                float scv = ldf(g, o, f) * rsqrtf(ldf(vv, o, f) + 1e-5f);
                float sh = ldf(bb, o, f) - ldf(mm, o, f) * scv;
#pragma unroll
                for (int nt = 0; nt < 4; nt++) {
                    int n = n0 + wn * 64 + nt * 16 + row;
                    int b = n / NPIX, hw = n - b * NPIX;
                    float val = acc[mt][nt][r] * scv + sh;
                    bf16 bv = (bf16)val;
                    if (o < 384) {
                        qb[((size_t)b * 384 + o) * NPIX + hw] = bv;
                    } else {
                        vb[((size_t)b * 1536 + (o - 768)) * MPAD + hw] = bv;
                    }
                }
            }
        }
    }
}

// ---------------- proj GEMM + BN -> output ----------------
__global__ __launch_bounds__(256) void gemm_proj_kernel(
    const bf16* __restrict__ ot, const bf16* __restrict__ w,
    const void* __restrict__ g, const void* __restrict__ bb,
    const void* __restrict__ mm, const void* __restrict__ vv, const int* __restrict__ flag,
    void* __restrict__ out, int b0) {
    __shared__ bf16 smem[6 * 128 * 32];   // 48KB -> 3 blocks/CU
    f32x4 acc[4][4];
#pragma unroll
    for (int i = 0; i < 4; i++)
#pragma unroll
        for (int j = 0; j < 4; j++) acc[i][j] = (f32x4){0.f, 0.f, 0.f, 0.f};
    int nwg = gridDim.x * gridDim.y;
    int l = xcd_swizzle(blockIdx.y * gridDim.x + blockIdx.x, nwg);
    int m0 = (l % gridDim.x) * 128, n0 = (l / gridDim.x) * 128;
    gemm_tile3<1536>(w + (size_t)m0 * 1536, ot + (size_t)n0 * 1536, smem, acc);
    int f = *flag;
    int wave = threadIdx.x >> 6, lane = threadIdx.x & 63;
    int wm = wave >> 1, wn = wave & 1, row = lane & 15, grp = lane >> 4;
#pragma unroll
    for (int mt = 0; mt < 4; mt++) {
#pragma unroll
        for (int r = 0; r < 4; r++) {
            int o = m0 + wm * 64 + mt * 16 + grp * 4 + r;
            float scv = ldf(g, o, f) * rsqrtf(ldf(vv, o, f) + 1e-5f);
            float sh = ldf(bb, o, f) - ldf(mm, o, f) * scv;
#pragma unroll
            for (int nt = 0; nt < 4; nt++) {
                int n = n0 + wn * 64 + nt * 16 + row;
                int b = n / NPIX, hw = n - b * NPIX;
                float val = acc[mt][nt][r] * scv + sh;
                size_t oidx = ((size_t)(b0 + b) * 384 + o) * NPIX + hw;
                if (f) ((float*)out)[oidx] = val;
                else ((bf16*)out)[oidx] = (bf16)val;
            }
        }
    }
}

// ---------------- depthwise 3x3 conv + BN, write transposed (b, hw, c) ----------------
__global__ void dwconv_kernel(const bf16* __restrict__ qb, const bf16* __restrict__ w,
                              const void* __restrict__ g, const void* __restrict__ bb,
                              const void* __restrict__ mm, const void* __restrict__ vv,
                              const int* __restrict__ flag, bf16* __restrict__ qt) {
    __shared__ bf16 tile[32][33];
    int f = *flag;
    int b = blockIdx.z;
    int c0 = blockIdx.y * 32, hw0 = blockIdx.x * 32;
    int tx = threadIdx.x, ty = threadIdx.y;
    int c = c0 + ty, hw = hw0 + tx;
    if (hw < NPIX) {
        int y = hw / 14, x = hw % 14;
        float acc = 0.f;
        const bf16* wp = w + c * 9;
        const bf16* qp = qb + ((size_t)b * 384 + c) * NPIX;
#pragma unroll
        for (int ky = 0; ky < 3; ky++) {
            int yy = y + ky - 1;
            if (yy < 0 || yy >= 14) continue;
#pragma unroll
            for (int kx = 0; kx < 3; kx++) {
                int xx = x + kx - 1;
                if (xx < 0 || xx >= 14) continue;
                acc += (float)qp[yy * 14 + xx] * (float)wp[ky * 3 + kx];
            }
        }
        float sc = ldf(g, c, f) * rsqrtf(ldf(vv, c, f) + 1e-5f);
        float sh = ldf(bb, c, f) - ldf(mm, c, f) * sc;
        tile[ty][tx] = (bf16)(acc * sc + sh);
    }
    __syncthreads();
    int hw2 = hw0 + ty, c2 = c0 + tx;
    if (hw2 < NPIX) qt[((size_t)b * NPIX + hw2) * CIN + c2] = tile[tx][ty];
}

// ---------------- attention per (b,h) ----------------
// Swapped-operand structure (register-resident P), V staged once into padded
// LDS, output transposed through per-wave LDS chunk for 64B-contiguous stores.
__global__ __launch_bounds__(256, 2) void attn_kernel(
    const bf16* __restrict__ qt, const bf16* __restrict__ ktp, const bf16* __restrict__ vb,
    const float* __restrict__ biasf, bf16* __restrict__ ot) {
    __shared__ bf16 Vs[128 * VSTRIDE];          // 59392 B
    __shared__ bf16 Osh[4][16 * OSTRIDE];       // 5120 B  (total 64512 <= 64KB)
    int nwg = gridDim.x * gridDim.y;
    int l = xcd_swizzle(blockIdx.y * gridDim.x + blockIdx.x, nwg);
    int h = l % NHEADS, b = l / NHEADS;
    int tid = threadIdx.x;
    int wave = tid >> 6, lane = tid & 63;
    int row = lane & 15, grp = lane >> 4;
    const float scale = 0.17677669529663687f;
    const f32x4 zf = {0.f, 0.f, 0.f, 0.f};

    // ---- stage V slice (128 x 224 bf16, contiguous 57344B) into padded LDS ----
    {
        const bf16* vsrc = vb + ((size_t)b * 1536 + h * 128) * MPAD;
#pragma unroll
        for (int it = 0; it < 14; it++) {
            int i = it * 256 + tid;               // 16B granule index, 3584 total
            int r = i / 28, gch = i - r * 28;     // 28 granules per d-row
            *(bf16x8*)(Vs + r * VSTRIDE + gch * 8) = *(const bf16x8*)(vsrc + (size_t)i * 8);
        }
    }
    __syncthreads();

    const bf16* vls = Vs + row * VSTRIDE + grp * 4;

    for (int nb = wave; nb < 13; nb += 4) {
        int n0 = nb * 16;
        int n = n0 + row;
        int nc = n > 195 ? 195 : n;

        // Q B-frag: Q[n][c = h*32 + grp*8 + j]
        bf16x8 aq = *(const bf16x8*)(qt + ((size_t)b * NPIX + nc) * CIN + h * 32 + grp * 8);

        // S^T: 14 MFMAs, K rows from global (12.5KB/head slice, L1/L2-resident)
        f32x4 sacc[14];
#pragma unroll
        for (int mt = 0; mt < 14; mt++) {
            int krow = mt * 16 + row;
            if (krow > 195) krow = 195;  // garbage rows overridden by -1e30 bias pad
            bf16x8 ak = *(const bf16x8*)(ktp + ((size_t)b * NPIX + krow) * CIN + h * 32 + grp * 8);
            sacc[mt] = __builtin_amdgcn_mfma_f32_16x16x32_bf16(ak, aq, zf, 0, 0, 0);
        }

        // bias add (vectorized via symmetry) + column max
        const float* bp = biasf + ((size_t)h * NPIX + nc) * MPAD + grp * 4;
        f32x4 mxv = {-3.4e38f, -3.4e38f, -3.4e38f, -3.4e38f};
#pragma unroll
        for (int mt = 0; mt < 14; mt++) {
            f32x4 bv = *(const f32x4*)(bp + mt * 16);
            f32x4 s = sacc[mt] * scale + bv;
            sacc[mt] = s;
            mxv = vmax4(mxv, s);
        }
        float mx = fmaxf(fmaxf(mxv[0], mxv[1]), fmaxf(mxv[2], mxv[3]));
        mx = fmaxf(mx, __shfl_xor(mx, 16));
        mx = fmaxf(mx, __shfl_xor(mx, 32));

        // exp + sum + convert to bf16 P-frags (in-register, no LDS round-trip)
        f32x4 sumv = zf;
        bf16x4 pf[14];
#pragma unroll
        for (int mt = 0; mt < 14; mt++) {
            f32x4 e;
#pragma unroll
            for (int r = 0; r < 4; r++) e[r] = __expf(sacc[mt][r] - mx);
            sumv += e;
            bf16x4 pb;
#pragma unroll
            for (int r = 0; r < 4; r++) pb[r] = (bf16)e[r];
            pf[mt] = pb;
        }
        float sum = (sumv[0] + sumv[1]) + (sumv[2] + sumv[3]);
        sum += __shfl_xor(sum, 16);
        sum += __shfl_xor(sum, 32);
        float inv = 1.f / sum;

        // PV: 112 K=16 MFMAs; V A-frags are 8B LDS reads (padded stride, ~2-way)
        f32x4 oacc[8];
#pragma unroll
        for (int dt = 0; dt < 8; dt++) oacc[dt] = zf;
#pragma unroll
        for (int mt = 0; mt < 14; mt++) {
            bf16x4 p = pf[mt];
#pragma unroll
            for (int dt = 0; dt < 8; dt++) {
                bf16x4 v4 = *(const bf16x4*)(vls + dt * 16 * VSTRIDE + mt * 16);
                oacc[dt] = mfma16(v4, p, oacc[dt]);
            }
        }

        // epilogue: normalize + ReLU, transpose 16x32-d chunks through per-wave LDS,
        // store as 64B-contiguous segments. n-guard on the store side.
        bf16* osw = Osh[wave];
        int r2 = lane >> 2, c2 = lane & 3;
        int n2 = n0 + r2;
        bf16* op = ot + ((size_t)b * NPIX + n2) * 1536 + h * 128;
#pragma unroll
        for (int dp = 0; dp < 4; dp++) {
#pragma unroll
            for (int u = 0; u < 2; u++) {
                int dt = dp * 2 + u;
                bf16x4 o4;
#pragma unroll
                for (int r = 0; r < 4; r++) {
                    float v = oacc[dt][r] * inv;
                    o4[r] = (bf16)(v > 0.f ? v : 0.f);
                }
                *(bf16x4*)(osw + row * OSTRIDE + u * 16 + grp * 4) = o4;
            }
            asm volatile("s_waitcnt lgkmcnt(0)" ::: "memory");
            if (n2 < NPIX) {
                bf16x8 ov = *(const bf16x8*)(osw + r2 * OSTRIDE + c2 * 8);
                *(bf16x8*)(op + dp * 32 + c2 * 8) = ov;
            }
            asm volatile("s_waitcnt lgkmcnt(0)" ::: "memory");
        }
    }
}

extern "C" void kernel_launch(void* const* d_in, const int* in_sizes, int n_in,
                              void* d_out, int out_size, void* d_ws, size_t ws_size,
                              hipStream_t stream) {
    const void* x      = d_in[0];
    const void* qkv_w  = d_in[1];
    const void* qkv_g  = d_in[2];
    const void* qkv_b  = d_in[3];
    const void* qkv_m  = d_in[4];
    const void* qkv_v  = d_in[5];
    const void* dw_w   = d_in[6];
    const void* dw_g   = d_in[7];
    const void* dw_b   = d_in[8];
    const void* dw_m   = d_in[9];
    const void* dw_v   = d_in[10];
    const void* proj_w = d_in[11];
    const void* proj_g = d_in[12];
    const void* proj_b = d_in[13];
    const void* proj_m = d_in[14];
    const void* proj_v = d_in[15];
    const void* ab     = d_in[16];
    const int*  idx    = (const int*)d_in[17];

    char* ws = (char*)d_ws;
    size_t off = 0;
    auto alloc = [&](size_t bytes) { void* p = ws + off; off += (bytes + 255) & ~(size_t)255; return p; };

    int*   flag = (int*)alloc(4);
    bf16*  wq   = (bf16*)alloc((size_t)N_WQ * 2);
    bf16*  wp   = (bf16*)alloc((size_t)N_WP * 2);
    bf16*  wd   = (bf16*)alloc((size_t)N_WD * 2);
    float* biasf= (float*)alloc((size_t)N_BI * 4);
    size_t fixed = off;

    const size_t s_xt = (size_t)NPIX * CIN;
    const size_t s_qb = (size_t)384 * NPIX;
    const size_t s_kt = (size_t)NPIX * 384;
    const size_t s_vb = (size_t)1536 * MPAD;
    const size_t s_ot = (size_t)NPIX * 1536;
    const size_t per_image = (s_xt + s_qb + s_kt + s_vb + s_ot) * 2;

    int CB = 128;
    while (CB > 32 && fixed + (size_t)CB * per_image > ws_size) CB >>= 1;

    bf16* xt  = (bf16*)alloc((size_t)CB * s_xt * 2);
    bf16* qb  = (bf16*)alloc((size_t)CB * s_qb * 2);
    bf16* ktp = (bf16*)alloc((size_t)CB * s_kt * 2);
    bf16* vb  = (bf16*)alloc((size_t)CB * s_vb * 2);
    bf16* ot  = (bf16*)alloc((size_t)CB * s_ot * 2);
    bf16* qt  = xt;  // xt dead after gemm_qkv; reuse for dwconv output

    detect_kernel<<<dim3(1), dim3(256), 0, stream>>>((const unsigned int*)x, flag);
    int nvpad = CB * 1536 * 7;
    long prep_total = (long)N_WQ + N_WP + N_WD + N_BI + nvpad;
    int prep_blocks = (int)((prep_total + 255) / 256);
    prep_kernel<<<dim3(prep_blocks), dim3(256), 0, stream>>>(qkv_w, proj_w, dw_w, ab, idx, flag,
                                                             wq, wp, wd, biasf, vb, nvpad);

    dim3 tb(32, 32);
    for (int b0 = 0; b0 < 128; b0 += CB) {
        int cb = (128 - b0 < CB) ? (128 - b0) : CB;
        int ntiles = (cb * NPIX) / 128;  // cb in {32,64,128} -> exact
        transpose_x_kernel<<<dim3(7, 12, cb), tb, 0, stream>>>(x, flag, xt, b0);
        gemm_qkv_kernel<<<dim3(18, ntiles), dim3(256), 0, stream>>>(xt, wq, qkv_g, qkv_b, qkv_m,
                                                                    qkv_v, flag, qb, ktp, vb);
        dwconv_kernel<<<dim3(7, 12, cb), tb, 0, stream>>>(qb, wd, dw_g, dw_b, dw_m, dw_v, flag, qt);
        attn_kernel<<<dim3(NHEADS, cb), dim3(256), 0, stream>>>(qt, ktp, vb, biasf, ot);
        gemm_proj_kernel<<<dim3(3, ntiles), dim3(256), 0, stream>>>(ot, wp, proj_g, proj_b, proj_m,
                                                                    proj_v, flag, d_out, b0);
    }
}

// Round 8
// 428.539 us; speedup vs baseline: 1.6263x; 1.0125x over previous
//
#include <hip/hip_runtime.h>

typedef __bf16 bf16;
typedef bf16 bf16x8 __attribute__((ext_vector_type(8)));
typedef bf16 bf16x4 __attribute__((ext_vector_type(4)));
typedef short short4v __attribute__((ext_vector_type(4)));
typedef float f32x4 __attribute__((ext_vector_type(4)));

#define NPIX 196
#define CIN 384
#define NHEADS 12
#define MPAD 224
#define VSTRIDE 232   // LDS row stride for V (bf16): ~2-way banks
#define OSTRIDE 40    // LDS row stride for store-transpose chunk
#define TSTRIDE 136   // LDS row stride for GEMM transpose epilogues (bf16)
#define TSF 136       // LDS row stride for proj f32 transpose epilogue

#define N_WQ (2304 * 384)
#define N_WP (384 * 1536)
#define N_WD (384 * 9)
#define N_BI (NHEADS * NPIX * MPAD)

// flag-aware scalar load: f=1 -> fp32 data, f=0 -> bf16 data
__device__ __forceinline__ float ldf(const void* p, size_t i, int f) {
    return f ? ((const float*)p)[i] : (float)((const bf16*)p)[i];
}

// async global->LDS, 16B per lane. LDS dest must be wave-uniform base + lane*16.
__device__ __forceinline__ void gld16(const void* g, void* lds_wave_base) {
    __builtin_amdgcn_global_load_lds(
        (const __attribute__((address_space(1))) void*)(unsigned long long)g,
        (__attribute__((address_space(3))) void*)(unsigned long long)lds_wave_base,
        16, 0, 0);
}

// bijective chunked XCD swizzle (m204)
__device__ __forceinline__ int xcd_swizzle(int orig, int nwg) {
    int q = nwg >> 3, r = nwg & 7;
    int xcd = orig & 7, idx = orig >> 3;
    return (xcd < r ? xcd * (q + 1) : r * (q + 1) + (xcd - r) * q) + idx;
}

// K=16 bf16 MFMA: B-frag layout matches the in-register P layout of swapped QK^T.
__device__ __forceinline__ f32x4 mfma16(bf16x4 a, bf16x4 b, f32x4 c) {
#if __has_builtin(__builtin_amdgcn_mfma_f32_16x16x16bf16_1k)
    return __builtin_amdgcn_mfma_f32_16x16x16bf16_1k(
        __builtin_bit_cast(short4v, a), __builtin_bit_cast(short4v, b), c, 0, 0, 0);
#else
    asm volatile("v_mfma_f32_16x16x16_bf16 %0, %1, %2, %0" : "+v"(c) : "v"(a), "v"(b));
    return c;
#endif
}

__device__ __forceinline__ f32x4 vmax4(f32x4 a, f32x4 b) {
    f32x4 r;
    r[0] = fmaxf(a[0], b[0]);
    r[1] = fmaxf(a[1], b[1]);
    r[2] = fmaxf(a[2], b[2]);
    r[3] = fmaxf(a[3], b[3]);
    return r;
}

// ---------------- dtype detector ----------------
__global__ void detect_kernel(const unsigned int* __restrict__ x, int* __restrict__ flag) {
    __shared__ int cnt;
    if (threadIdx.x == 0) cnt = 0;
    __syncthreads();
    int c = 0;
#pragma unroll
    for (int k = 0; k < 8; k++) {
        unsigned int w = x[threadIdx.x * 8 + k];
        unsigned int e = (w >> 7) & 0xFFu;
        if (e > 200u) c++;
    }
    atomicAdd(&cnt, c);
    __syncthreads();
    if (threadIdx.x == 0) *flag = (cnt >= 16) ? 1 : 0;
}

// ---------------- fused prep: weight converts + bias gather + V-pad zero ----------------
__global__ void prep_kernel(const void* __restrict__ qkv_w, const void* __restrict__ proj_w,
                            const void* __restrict__ dw_w, const void* __restrict__ ab,
                            const int* __restrict__ idx, const int* __restrict__ flag,
                            bf16* __restrict__ wq, bf16* __restrict__ wp, bf16* __restrict__ wd,
                            float* __restrict__ biasf, bf16* __restrict__ vb, int nvpad) {
    int f = *flag;
    long t = (long)blockIdx.x * 256 + threadIdx.x;
    if (t < N_WQ) { wq[t] = (bf16)ldf(qkv_w, t, f); return; }
    t -= N_WQ;
    if (t < N_WP) { wp[t] = (bf16)ldf(proj_w, t, f); return; }
    t -= N_WP;
    if (t < N_WD) { wd[t] = (bf16)ldf(dw_w, t, f); return; }
    t -= N_WD;
    if (t < N_BI) {
        int h = (int)(t / (NPIX * MPAD));
        int rem = (int)(t - (long)h * (NPIX * MPAD));
        int n = rem / MPAD, m = rem - n * MPAD;
        biasf[t] = (m < NPIX) ? ldf(ab, h * NPIX + idx[n * NPIX + m], f) : -1e30f;
        return;
    }
    t -= N_BI;
    if (t < nvpad) {
        long r = t / 7, c = t - r * 7;
        *(unsigned long long*)(vb + r * MPAD + NPIX + c * 4) = 0ull;
    }
}

// ---------------- transpose x: (b, c, hw) -> (b, hw, c), canonical bf16 ----------------
__global__ void transpose_x_kernel(const void* __restrict__ x, const int* __restrict__ flag,
                                   bf16* __restrict__ xt, int b0) {
    __shared__ bf16 tile[32][33];
    int f = *flag;
    int b = blockIdx.z, gb = b0 + b;
    int c0 = blockIdx.y * 32;
    int hw0 = blockIdx.x * 32;
    int tx = threadIdx.x, ty = threadIdx.y;
    int hw = hw0 + tx, c = c0 + ty;
    if (hw < NPIX) tile[ty][tx] = (bf16)ldf(x, ((size_t)gb * CIN + c) * NPIX + hw, f);
    __syncthreads();
    int hw2 = hw0 + ty, c2 = c0 + tx;
    if (hw2 < NPIX) xt[((size_t)b * NPIX + hw2) * CIN + c2] = tile[tx][ty];
}

// ---------------- 128x128 GEMM mainloop: r4-verified dbuf + counted vmcnt ----------------
// Per step: issue next-tile gld16 -> vmcnt(8) (drains PREVIOUS tile only) -> raw
// s_barrier -> ds_read + MFMA -> raw s_barrier. 64KB LDS, 2 blocks/CU.
__device__ __forceinline__ void gemm_tile(const bf16* __restrict__ A, const bf16* __restrict__ B,
                                          int K, bf16* smem, f32x4 acc[4][4]) {
    int tid = threadIdx.x;
    int wave = tid >> 6, lane = tid & 63;
    int wm = wave >> 1, wn = wave & 1;
    int row = lane & 15, grp = lane >> 4;
    int sr = lane >> 3;
    int scg = (lane & 7) ^ sr;
    const int BUF = 128 * 64;
    bf16* As = smem;
    bf16* Bs = smem + 2 * BUF;
    const bf16* Ag = A + (size_t)(wave * 8 + sr) * K + scg * 8;
    const bf16* Bg = B + (size_t)(wave * 8 + sr) * K + scg * 8;
#pragma unroll
    for (int p = 0; p < 4; p++) {
        gld16(Ag + (size_t)(p * 32) * K, As + (p * 256 + wave * 64) * 8);
        gld16(Bg + (size_t)(p * 32) * K, Bs + (p * 256 + wave * 64) * 8);
    }
    int cur = 0;
#pragma unroll 1
    for (int kb = 0; kb < K; kb += 64) {
        if (kb + 64 < K) {
            bf16* Asn = As + (cur ^ 1) * BUF;
            bf16* Bsn = Bs + (cur ^ 1) * BUF;
#pragma unroll
            for (int p = 0; p < 4; p++) {
                gld16(Ag + (size_t)(p * 32) * K + kb + 64, Asn + (p * 256 + wave * 64) * 8);
                gld16(Bg + (size_t)(p * 32) * K + kb + 64, Bsn + (p * 256 + wave * 64) * 8);
            }
            __builtin_amdgcn_sched_barrier(0);
            asm volatile("s_waitcnt vmcnt(8)" ::: "memory");
        } else {
            __builtin_amdgcn_sched_barrier(0);
            asm volatile("s_waitcnt vmcnt(0)" ::: "memory");
        }
        __builtin_amdgcn_s_barrier();
        __builtin_amdgcn_sched_barrier(0);
        const bf16* Asc = As + cur * BUF;
        const bf16* Bsc = Bs + cur * BUF;
#pragma unroll
        for (int ki = 0; ki < 2; ki++) {
            bf16x8 af[4], bfr[4];
#pragma unroll
            for (int t = 0; t < 4; t++) {
                int ra = wm * 64 + t * 16 + row;
                af[t] = *(const bf16x8*)(Asc + ra * 64 + (((ki * 4 + grp) ^ (ra & 7)) * 8));
                int rb = wn * 64 + t * 16 + row;
                bfr[t] = *(const bf16x8*)(Bsc + rb * 64 + (((ki * 4 + grp) ^ (rb & 7)) * 8));
            }
#pragma unroll
            for (int mt = 0; mt < 4; mt++)
#pragma unroll
                for (int nt = 0; nt < 4; nt++)
                    acc[mt][nt] =
                        __builtin_amdgcn_mfma_f32_16x16x32_bf16(af[mt], bfr[nt], acc[mt][nt], 0, 0, 0);
        }
        __builtin_amdgcn_sched_barrier(0);
        __builtin_amdgcn_s_barrier();
        cur ^= 1;
    }
    __builtin_amdgcn_sched_barrier(0);
}

// ---------------- QKV GEMM + BN, ALL routes via LDS-transpose coalesced stores ----------------
__global__ __launch_bounds__(256) void gemm_qkv_kernel(
    const bf16* __restrict__ xt, const bf16* __restrict__ w,
    const void* __restrict__ g, const void* __restrict__ bb,
    const void* __restrict__ mm, const void* __restrict__ vv, const int* __restrict__ flag,
    bf16* __restrict__ qb, bf16* __restrict__ kt, bf16* __restrict__ vb) {
    __shared__ bf16 smem[4 * 128 * 64];   // 64KB dbuf; reused as transpose buf after loop
    f32x4 acc[4][4];
#pragma unroll
    for (int i = 0; i < 4; i++)
#pragma unroll
        for (int j = 0; j < 4; j++) acc[i][j] = (f32x4){0.f, 0.f, 0.f, 0.f};
    int nwg = gridDim.x * gridDim.y;
    int l = xcd_swizzle(blockIdx.y * gridDim.x + blockIdx.x, nwg);
    int m0 = (l % gridDim.x) * 128, n0 = (l / gridDim.x) * 128;
    gemm_tile(w + (size_t)m0 * CIN, xt + (size_t)n0 * CIN, CIN, smem, acc);
    int f = *flag;
    int tid = threadIdx.x;
    int wave = tid >> 6, lane = tid & 63;
    int wm = wave >> 1, wn = wave & 1, row = lane & 15, grp = lane >> 4;
    bf16* tbuf = smem;  // [128][TSTRIDE], 34816B
    if (m0 >= 384 && m0 < 768) {
        // k route: n-major [n][o]; kt row addr is LINEAR in n (n*384).
#pragma unroll
        for (int mt = 0; mt < 4; mt++) {
#pragma unroll
            for (int r = 0; r < 4; r++) {
                int ol = wm * 64 + mt * 16 + grp * 4 + r;
                int o = m0 + ol;
                float scv = ldf(g, o, f) * rsqrtf(ldf(vv, o, f) + 1e-5f);
                float sh = ldf(bb, o, f) - ldf(mm, o, f) * scv;
#pragma unroll
                for (int nt = 0; nt < 4; nt++) {
                    int nl = wn * 64 + nt * 16 + row;
                    tbuf[nl * TSTRIDE + ol] = (bf16)(acc[mt][nt][r] * scv + sh);
                }
            }
        }
        __syncthreads();
#pragma unroll
        for (int it = 0; it < 8; it++) {
            int g2 = it * 256 + tid;
            int nl = g2 >> 4, ch = g2 & 15;
            *(bf16x8*)(kt + (size_t)(n0 + nl) * CIN + (m0 - 384) + ch * 8) =
                *(const bf16x8*)(tbuf + nl * TSTRIDE + ch * 8);
        }
    } else {
        // q / v routes: o-major [o][n]; rows are (b,o)-major with hw contiguous.
#pragma unroll
        for (int mt = 0; mt < 4; mt++) {
#pragma unroll
            for (int r = 0; r < 4; r++) {
                int ol = wm * 64 + mt * 16 + grp * 4 + r;
                int o = m0 + ol;
                float scv = ldf(g, o, f) * rsqrtf(ldf(vv, o, f) + 1e-5f);
                float sh = ldf(bb, o, f) - ldf(mm, o, f) * scv;
#pragma unroll
                for (int nt = 0; nt < 4; nt++) {
                    int nl = wn * 64 + nt * 16 + row;
                    tbuf[ol * TSTRIDE + nl] = (bf16)(acc[mt][nt][r] * scv + sh);
                }
            }
        }
        __syncthreads();
        bool isq = (m0 < 384);
        bf16* dst = isq ? qb : vb;
        int ostride = isq ? NPIX : MPAD;
        int obase = isq ? m0 : (m0 - 768);
        int orow_mul = isq ? 384 : 1536;
#pragma unroll
        for (int it = 0; it < 8; it++) {
            int g2 = it * 256 + tid;
            int ol = g2 >> 4, ch = g2 & 15;
            int o = obase + ol;
            int ng = n0 + ch * 8;
            int b0i = ng / NPIX, hw0 = ng - b0i * NPIX;
            const bf16* src = tbuf + ol * TSTRIDE + ch * 8;
            if (hw0 <= NPIX - 8) {
                // hw0 % 4 == 0 by construction -> 8B-aligned stores
                bf16* d = dst + ((size_t)b0i * orow_mul + o) * ostride + hw0;
                *(bf16x4*)d = *(const bf16x4*)src;
                *(bf16x4*)(d + 4) = *(const bf16x4*)(src + 4);
            } else {
#pragma unroll
                for (int j = 0; j < 8; j++) {
                    int n2 = ng + j;
                    int bj = n2 / NPIX, hwj = n2 - bj * NPIX;
                    dst[((size_t)bj * orow_mul + o) * ostride + hwj] = src[j];
                }
            }
        }
    }
}

// ---------------- proj GEMM + BN -> output (f32 path via LDS-transpose) ----------------
__global__ __launch_bounds__(256) void gemm_proj_kernel(
    const bf16* __restrict__ ot, const bf16* __restrict__ w,
    const void* __restrict__ g, const void* __restrict__ bb,
    const void* __restrict__ mm, const void* __restrict__ vv, const int* __restrict__ flag,
    void* __restrict__ out, int b0) {
    __shared__ bf16 smem[4 * 128 * 64];
    f32x4 acc[4][4];
#pragma unroll
    for (int i = 0; i < 4; i++)
#pragma unroll
        for (int j = 0; j < 4; j++) acc[i][j] = (f32x4){0.f, 0.f, 0.f, 0.f};
    int nwg = gridDim.x * gridDim.y;
    int l = xcd_swizzle(blockIdx.y * gridDim.x + blockIdx.x, nwg);
    int m0 = (l % gridDim.x) * 128, n0 = (l / gridDim.x) * 128;
    gemm_tile(w + (size_t)m0 * 1536, ot + (size_t)n0 * 1536, 1536, smem, acc);
    int f = *flag;
    int tid = threadIdx.x;
    int wave = tid >> 6, lane = tid & 63;
    int wm = wave >> 1, wn = wave & 1, row = lane & 15, grp = lane >> 4;
    if (f) {
        // f32 output: two 64-row passes through [64][TSF] f32 tbuf, 16B stores.
        float* tb = (float*)smem;   // 64*TSF*4 = 34816B
#pragma unroll
        for (int half = 0; half < 2; half++) {
            if (wm == half) {
#pragma unroll
                for (int mt = 0; mt < 4; mt++) {
#pragma unroll
                    for (int r = 0; r < 4; r++) {
                        int ol = mt * 16 + grp * 4 + r;
                        int o = m0 + half * 64 + ol;
                        float scv = ldf(g, o, f) * rsqrtf(ldf(vv, o, f) + 1e-5f);
                        float sh = ldf(bb, o, f) - ldf(mm, o, f) * scv;
#pragma unroll
                        for (int nt = 0; nt < 4; nt++) {
                            int nl = wn * 64 + nt * 16 + row;
                            tb[ol * TSF + nl] = acc[mt][nt][r] * scv + sh;
                        }
                    }
                }
            }
            __syncthreads();
            float* outf = (float*)out;
#pragma unroll
            for (int it = 0; it < 8; it++) {
                int g2 = it * 256 + tid;
                int ol = g2 >> 5, ch = g2 & 31;
                int o = m0 + half * 64 + ol;
                int ng = n0 + ch * 4;
                int b0i = ng / NPIX, hw0 = ng - b0i * NPIX;
                const float* src = tb + ol * TSF + ch * 4;
                if (hw0 <= NPIX - 4) {
                    // hw0 % 4 == 0 -> 16B-aligned
                    *(f32x4*)(outf + ((size_t)(b0 + b0i) * 384 + o) * NPIX + hw0) =
                        *(const f32x4*)src;
                } else {
#pragma unroll
                    for (int j = 0; j < 4; j++) {
                        int n2 = ng + j;
                        int bj = n2 / NPIX, hwj = n2 - bj * NPIX;
                        outf[((size_t)(b0 + bj) * 384 + o) * NPIX + hwj] = src[j];
                    }
                }
            }
            __syncthreads();
        }
    } else {
        // bf16 output: scalar (correctness path)
#pragma unroll
        for (int mt = 0; mt < 4; mt++) {
#pragma unroll
            for (int r = 0; r < 4; r++) {
                int o = m0 + wm * 64 + mt * 16 + grp * 4 + r;
                float scv = ldf(g, o, f) * rsqrtf(ldf(vv, o, f) + 1e-5f);
                float sh = ldf(bb, o, f) - ldf(mm, o, f) * scv;
#pragma unroll
                for (int nt = 0; nt < 4; nt++) {
                    int n = n0 + wn * 64 + nt * 16 + row;
                    int b = n / NPIX, hw = n - b * NPIX;
                    ((bf16*)out)[((size_t)(b0 + b) * 384 + o) * NPIX + hw] =
                        (bf16)(acc[mt][nt][r] * scv + sh);
                }
            }
        }
    }
}

// ---------------- depthwise 3x3 conv + BN, write transposed (b, hw, c) ----------------
__global__ void dwconv_kernel(const bf16* __restrict__ qb, const bf16* __restrict__ w,
                              const void* __restrict__ g, const void* __restrict__ bb,
                              const void* __restrict__ mm, const void* __restrict__ vv,
                              const int* __restrict__ flag, bf16* __restrict__ qt) {
    __shared__ bf16 tile[32][33];
    int f = *flag;
    int b = blockIdx.z;
    int c0 = blockIdx.y * 32, hw0 = blockIdx.x * 32;
    int tx = threadIdx.x, ty = threadIdx.y;
    int c = c0 + ty, hw = hw0 + tx;
    if (hw < NPIX) {
        int y = hw / 14, x = hw % 14;
        float acc = 0.f;
        const bf16* wp = w + c * 9;
        const bf16* qp = qb + ((size_t)b * 384 + c) * NPIX;
#pragma unroll
        for (int ky = 0; ky < 3; ky++) {
            int yy = y + ky - 1;
            if (yy < 0 || yy >= 14) continue;
#pragma unroll
            for (int kx = 0; kx < 3; kx++) {
                int xx = x + kx - 1;
                if (xx < 0 || xx >= 14) continue;
                acc += (float)qp[yy * 14 + xx] * (float)wp[ky * 3 + kx];
            }
        }
        float sc = ldf(g, c, f) * rsqrtf(ldf(vv, c, f) + 1e-5f);
        float sh = ldf(bb, c, f) - ldf(mm, c, f) * sc;
        tile[ty][tx] = (bf16)(acc * sc + sh);
    }
    __syncthreads();
    int hw2 = hw0 + ty, c2 = c0 + tx;
    if (hw2 < NPIX) qt[((size_t)b * NPIX + hw2) * CIN + c2] = tile[tx][ty];
}

// ---------------- attention per (b,h) ----------------
__global__ __launch_bounds__(256, 2) void attn_kernel(
    const bf16* __restrict__ qt, const bf16* __restrict__ ktp, const bf16* __restrict__ vb,
    const float* __restrict__ biasf, bf16* __restrict__ ot) {
    __shared__ bf16 Vs[128 * VSTRIDE];          // 59392 B
    __shared__ bf16 Osh[4][16 * OSTRIDE];       // 5120 B
    int nwg = gridDim.x * gridDim.y;
    int l = xcd_swizzle(blockIdx.y * gridDim.x + blockIdx.x, nwg);
    int h = l % NHEADS, b = l / NHEADS;
    int tid = threadIdx.x;
    int wave = tid >> 6, lane = tid & 63;
    int row = lane & 15, grp = lane >> 4;
    const float scale = 0.17677669529663687f;
    const f32x4 zf = {0.f, 0.f, 0.f, 0.f};

    {
        const bf16* vsrc = vb + ((size_t)b * 1536 + h * 128) * MPAD;
#pragma unroll
        for (int it = 0; it < 14; it++) {
            int i = it * 256 + tid;
            int r = i / 28, gch = i - r * 28;
            *(bf16x8*)(Vs + r * VSTRIDE + gch * 8) = *(const bf16x8*)(vsrc + (size_t)i * 8);
        }
    }
    __syncthreads();

    const bf16* vls = Vs + row * VSTRIDE + grp * 4;

    for (int nb = wave; nb < 13; nb += 4) {
        int n0 = nb * 16;
        int n = n0 + row;
        int nc = n > 195 ? 195 : n;

        bf16x8 aq = *(const bf16x8*)(qt + ((size_t)b * NPIX + nc) * CIN + h * 32 + grp * 8);

        // S^T: 14 MFMAs (setprio cluster)
        f32x4 sacc[14];
        __builtin_amdgcn_s_setprio(1);
#pragma unroll
        for (int mt = 0; mt < 14; mt++) {
            int krow = mt * 16 + row;
            if (krow > 195) krow = 195;
            bf16x8 ak = *(const bf16x8*)(ktp + ((size_t)b * NPIX + krow) * CIN + h * 32 + grp * 8);
            sacc[mt] = __builtin_amdgcn_mfma_f32_16x16x32_bf16(ak, aq, zf, 0, 0, 0);
        }
        __builtin_amdgcn_s_setprio(0);

        const float* bp = biasf + ((size_t)h * NPIX + nc) * MPAD + grp * 4;
        f32x4 mxv = {-3.4e38f, -3.4e38f, -3.4e38f, -3.4e38f};
#pragma unroll
        for (int mt = 0; mt < 14; mt++) {
            f32x4 bv = *(const f32x4*)(bp + mt * 16);
            f32x4 s = sacc[mt] * scale + bv;
            sacc[mt] = s;
            mxv = vmax4(mxv, s);
        }
        float mx = fmaxf(fmaxf(mxv[0], mxv[1]), fmaxf(mxv[2], mxv[3]));
        mx = fmaxf(mx, __shfl_xor(mx, 16));
        mx = fmaxf(mx, __shfl_xor(mx, 32));

        f32x4 sumv = zf;
        bf16x4 pf[14];
#pragma unroll
        for (int mt = 0; mt < 14; mt++) {
            f32x4 e;
#pragma unroll
            for (int r = 0; r < 4; r++) e[r] = __expf(sacc[mt][r] - mx);
            sumv += e;
            bf16x4 pb;
#pragma unroll
            for (int r = 0; r < 4; r++) pb[r] = (bf16)e[r];
            pf[mt] = pb;
        }
        float sum = (sumv[0] + sumv[1]) + (sumv[2] + sumv[3]);
        sum += __shfl_xor(sum, 16);
        sum += __shfl_xor(sum, 32);
        float inv = 1.f / sum;

        // PV: 112 K=16 MFMAs (setprio cluster)
        f32x4 oacc[8];
#pragma unroll
        for (int dt = 0; dt < 8; dt++) oacc[dt] = zf;
        __builtin_amdgcn_s_setprio(1);
#pragma unroll
        for (int mt = 0; mt < 14; mt++) {
            bf16x4 p = pf[mt];
#pragma unroll
            for (int dt = 0; dt < 8; dt++) {
                bf16x4 v4 = *(const bf16x4*)(vls + dt * 16 * VSTRIDE + mt * 16);
                oacc[dt] = mfma16(v4, p, oacc[dt]);
            }
        }
        __builtin_amdgcn_s_setprio(0);

        bf16* osw = Osh[wave];
        int r2 = lane >> 2, c2 = lane & 3;
        int n2 = n0 + r2;
        bf16* op = ot + ((size_t)b * NPIX + n2) * 1536 + h * 128;
#pragma unroll
        for (int dp = 0; dp < 4; dp++) {
#pragma unroll
            for (int u = 0; u < 2; u++) {
                int dt = dp * 2 + u;
                bf16x4 o4;
#pragma unroll
                for (int r = 0; r < 4; r++) {
                    float v = oacc[dt][r] * inv;
                    o4[r] = (bf16)(v > 0.f ? v : 0.f);
                }
                *(bf16x4*)(osw + row * OSTRIDE + u * 16 + grp * 4) = o4;
            }
            asm volatile("s_waitcnt lgkmcnt(0)" ::: "memory");
            if (n2 < NPIX) {
                bf16x8 ov = *(const bf16x8*)(osw + r2 * OSTRIDE + c2 * 8);
                *(bf16x8*)(op + dp * 32 + c2 * 8) = ov;
            }
            asm volatile("s_waitcnt lgkmcnt(0)" ::: "memory");
        }
    }
}

extern "C" void kernel_launch(void* const* d_in, const int* in_sizes, int n_in,
                              void* d_out, int out_size, void* d_ws, size_t ws_size,
                              hipStream_t stream) {
    const void* x      = d_in[0];
    const void* qkv_w  = d_in[1];
    const void* qkv_g  = d_in[2];
    const void* qkv_b  = d_in[3];
    const void* qkv_m  = d_in[4];
    const void* qkv_v  = d_in[5];
    const void* dw_w   = d_in[6];
    const void* dw_g   = d_in[7];
    const void* dw_b   = d_in[8];
    const void* dw_m   = d_in[9];
    const void* dw_v   = d_in[10];
    const void* proj_w = d_in[11];
    const void* proj_g = d_in[12];
    const void* proj_b = d_in[13];
    const void* proj_m = d_in[14];
    const void* proj_v = d_in[15];
    const void* ab     = d_in[16];
    const int*  idx    = (const int*)d_in[17];

    char* ws = (char*)d_ws;
    size_t off = 0;
    auto alloc = [&](size_t bytes) { void* p = ws + off; off += (bytes + 255) & ~(size_t)255; return p; };

    int*   flag = (int*)alloc(4);
    bf16*  wq   = (bf16*)alloc((size_t)N_WQ * 2);
    bf16*  wp   = (bf16*)alloc((size_t)N_WP * 2);
    bf16*  wd   = (bf16*)alloc((size_t)N_WD * 2);
    float* biasf= (float*)alloc((size_t)N_BI * 4);
    size_t fixed = off;

    const size_t s_xt = (size_t)NPIX * CIN;
    const size_t s_qb = (size_t)384 * NPIX;
    const size_t s_kt = (size_t)NPIX * 384;
    const size_t s_vb = (size_t)1536 * MPAD;
    const size_t s_ot = (size_t)NPIX * 1536;
    const size_t per_image = (s_xt + s_qb + s_kt + s_vb + s_ot) * 2;

    int CB = 128;
    while (CB > 32 && fixed + (size_t)CB * per_image > ws_size) CB >>= 1;

    bf16* xt  = (bf16*)alloc((size_t)CB * s_xt * 2);
    bf16* qb  = (bf16*)alloc((size_t)CB * s_qb * 2);
    bf16* ktp = (bf16*)alloc((size_t)CB * s_kt * 2);
    bf16* vb  = (bf16*)alloc((size_t)CB * s_vb * 2);
    bf16* ot  = (bf16*)alloc((size_t)CB * s_ot * 2);
    bf16* qt  = xt;  // xt dead after gemm_qkv; reuse for dwconv output

    detect_kernel<<<dim3(1), dim3(256), 0, stream>>>((const unsigned int*)x, flag);
    int nvpad = CB * 1536 * 7;
    long prep_total = (long)N_WQ + N_WP + N_WD + N_BI + nvpad;
    int prep_blocks = (int)((prep_total + 255) / 256);
    prep_kernel<<<dim3(prep_blocks), dim3(256), 0, stream>>>(qkv_w, proj_w, dw_w, ab, idx, flag,
                                                             wq, wp, wd, biasf, vb, nvpad);

    dim3 tb(32, 32);
    for (int b0 = 0; b0 < 128; b0 += CB) {
        int cb = (128 - b0 < CB) ? (128 - b0) : CB;
        int ntiles = (cb * NPIX) / 128;  // cb in {32,64,128} -> exact
        transpose_x_kernel<<<dim3(7, 12, cb), tb, 0, stream>>>(x, flag, xt, b0);
        gemm_qkv_kernel<<<dim3(18, ntiles), dim3(256), 0, stream>>>(xt, wq, qkv_g, qkv_b, qkv_m,
                                                                    qkv_v, flag, qb, ktp, vb);
        dwconv_kernel<<<dim3(7, 12, cb), tb, 0, stream>>>(qb, wd, dw_g, dw_b, dw_m, dw_v, flag, qt);
        attn_kernel<<<dim3(NHEADS, cb), dim3(256), 0, stream>>>(qt, ktp, vb, biasf, ot);
        gemm_proj_kernel<<<dim3(3, ntiles), dim3(256), 0, stream>>>(ot, wp, proj_g, proj_b, proj_m,
                                                                    proj_v, flag, d_out, b0);
    }
}